// Round 1
// baseline (3133.967 us; speedup 1.0000x reference)
//
#include <hip/hip_runtime.h>
#include <math.h>

#define HW   4096
#define CDIM 256

// ws layout (float offsets)
#define COMB_SZ  (8ULL*512*HW)
#define VBUF_SZ  (8ULL*256*HW)
#define MASK_SZ  (8ULL*36*HW)

// d_out layout (float offsets)
#define FUSED_SZ (4ULL*256*HW)
#define OFF_SZ   (4ULL*72*HW)

// ---------------------------------------------------------------------------
// Kernel 1: QKV 1x1 convs as tiled GEMM.  Output rows 0..511 -> comb (Q|K),
// rows 512..767 -> V.  Block = 64 outputs x 64 pixels, 256 thr, 4x4 micro.
// ---------------------------------------------------------------------------
__global__ __launch_bounds__(256) void qkv_gemm(
    const float* __restrict__ rife, const float* __restrict__ d0, const float* __restrict__ d1,
    const float* __restrict__ wq, const float* __restrict__ bq,
    const float* __restrict__ wk, const float* __restrict__ bk,
    const float* __restrict__ wv, const float* __restrict__ bv,
    float* __restrict__ comb, float* __restrict__ vbuf)
{
    const int s    = blockIdx.z;
    const int o0   = blockIdx.y * 64;
    const int pix0 = blockIdx.x * 64;
    const int t    = threadIdx.x;

    const float* dsrc = (s < 4 ? d0 : d1) + (size_t)(s & 3) * CDIM * HW;
    const float* X; const float* Wm; const float* bias; float* outp;
    if (o0 < 256) {
        X = rife + (size_t)(s & 3) * CDIM * HW;
        Wm = wq + (size_t)o0 * CDIM; bias = bq + o0;
        outp = comb + (size_t)s * 512 * HW + (size_t)o0 * HW;
    } else if (o0 < 512) {
        X = dsrc;
        Wm = wk + (size_t)(o0 - 256) * CDIM; bias = bk + (o0 - 256);
        outp = comb + (size_t)s * 512 * HW + (size_t)o0 * HW;
    } else {
        X = dsrc;
        Wm = wv + (size_t)(o0 - 512) * CDIM; bias = bv + (o0 - 512);
        outp = vbuf + (size_t)s * 256 * HW + (size_t)(o0 - 512) * HW;
    }

    __shared__ float Xs[16][64];
    __shared__ float Wls[64][17];

    const int tx = t & 15, ty = t >> 4;
    float acc[4][4] = {};

    for (int c0 = 0; c0 < 256; c0 += 16) {
        #pragma unroll
        for (int r = 0; r < 4; ++r) {
            int idx = t + r * 256;
            int kc = idx >> 6, pp = idx & 63;
            Xs[kc][pp] = X[(size_t)(c0 + kc) * HW + pix0 + pp];
        }
        #pragma unroll
        for (int r = 0; r < 4; ++r) {
            int idx = t + r * 256;
            int oo = idx >> 4, kc = idx & 15;
            Wls[oo][kc] = Wm[(size_t)oo * CDIM + c0 + kc];
        }
        __syncthreads();
        #pragma unroll
        for (int kc = 0; kc < 16; ++kc) {
            float a[4], bb[4];
            #pragma unroll
            for (int mi = 0; mi < 4; ++mi) a[mi] = Wls[ty * 4 + mi][kc];
            #pragma unroll
            for (int ni = 0; ni < 4; ++ni) bb[ni] = Xs[kc][tx * 4 + ni];
            #pragma unroll
            for (int mi = 0; mi < 4; ++mi)
                #pragma unroll
                for (int ni = 0; ni < 4; ++ni)
                    acc[mi][ni] += a[mi] * bb[ni];
        }
        __syncthreads();
    }
    #pragma unroll
    for (int mi = 0; mi < 4; ++mi) {
        float bz = bias[ty * 4 + mi];
        float4 v = make_float4(acc[mi][0] + bz, acc[mi][1] + bz,
                               acc[mi][2] + bz, acc[mi][3] + bz);
        *(float4*)(outp + (size_t)(ty * 4 + mi) * HW + pix0 + tx * 4) = v;
    }
}

// ---------------------------------------------------------------------------
// Kernel 2: 3x3 conv (512 -> 108 ch, pad 1).  Block = (s, h): 108 o x 64 w.
// Channels <72 -> offset (raw) into d_out; >=72 -> sigmoid -> mask ws.
// ---------------------------------------------------------------------------
__global__ __launch_bounds__(256) void offconv(
    const float* __restrict__ comb, const float* __restrict__ w_off,
    const float* __restrict__ b_off,
    float* __restrict__ dout, float* __restrict__ mask_ws)
{
    const int h = blockIdx.x;
    const int s = blockIdx.y;
    const int t = threadIdx.x;
    const int w = t & 63;
    const int og = t >> 6;   // 0..3, each owns 27 output channels

    __shared__ float tile[8][3][66];
    __shared__ __align__(16) float wl[108][8][12];

    float acc[27] = {};
    const float* cbase = comb + (size_t)s * 512 * HW;

    for (int c0 = 0; c0 < 512; c0 += 8) {
        __syncthreads();
        for (int idx = t; idx < 1584; idx += 256) {
            int ck = idx / 198; int rem = idx % 198;
            int ky = rem / 66;  int xi = rem % 66;
            int hh = h + ky - 1; int xx = xi - 1;
            float v = 0.f;
            if (hh >= 0 && hh < 64 && xx >= 0 && xx < 64)
                v = cbase[(size_t)(c0 + ck) * HW + hh * 64 + xx];
            tile[ck][ky][xi] = v;
        }
        for (int idx = t; idx < 7776; idx += 256) {
            int o = idx / 72; int rem = idx % 72;
            int ck = rem / 9; int kk = rem % 9;
            wl[o][ck][kk] = w_off[(size_t)o * 512 * 9 + (size_t)(c0 + ck) * 9 + kk];
        }
        __syncthreads();
        for (int ck = 0; ck < 8; ++ck) {
            float r[9];
            #pragma unroll
            for (int ky = 0; ky < 3; ++ky)
                #pragma unroll
                for (int kx = 0; kx < 3; ++kx)
                    r[ky * 3 + kx] = tile[ck][ky][w + kx];
            for (int j = 0; j < 27; ++j) {
                const float* wp = wl[og * 27 + j][ck];
                float a0 = r[0]*wp[0] + r[1]*wp[1] + r[2]*wp[2];
                float a1 = r[3]*wp[3] + r[4]*wp[4] + r[5]*wp[5];
                float a2 = r[6]*wp[6] + r[7]*wp[7] + r[8]*wp[8];
                acc[j] += a0 + a1 + a2;
            }
        }
    }
    for (int j = 0; j < 27; ++j) {
        int o = og * 27 + j;
        float v = acc[j] + b_off[o];
        if (o < 72) {
            size_t base = FUSED_SZ + (s < 4 ? 0 : OFF_SZ) + (size_t)(s & 3) * 72 * HW;
            dout[base + (size_t)o * HW + h * 64 + w] = v;
        } else {
            mask_ws[(size_t)s * 36 * HW + (size_t)(o - 72) * HW + h * 64 + w] =
                1.f / (1.f + expf(-v));
        }
    }
}

// ---------------------------------------------------------------------------
// Kernel 3: deformable conv + residual fuse.  Block = (b, g, h).
// For both sb=b and sb=b+4: 9 taps, bilinear-gather V tile into LDS, then
// 64o x 64w x 64i GEMM accumulate.  Epilogue: fused = rife + gamma*acc.
// ---------------------------------------------------------------------------
__global__ __launch_bounds__(256) void dcn_fuse(
    const float* __restrict__ rife, const float* __restrict__ dcn_w,
    const float* __restrict__ gamma,
    const float* __restrict__ vbuf, const float* __restrict__ mask_ws,
    float* __restrict__ dout)
{
    const int h = blockIdx.x;
    const int g = blockIdx.y;
    const int b = blockIdx.z;
    const int t = threadIdx.x;
    const int w = t & 63;
    const int og = t >> 6;

    __shared__ __align__(16) float samp[64][64];
    __shared__ __align__(16) float wkl[64][64];
    __shared__ float cw[4][64];
    __shared__ int   cidx[4][64];

    float acc[16] = {};

    for (int k = 0; k < 9; ++k) {
        __syncthreads();   // protect wkl/samp from previous iteration readers
        for (int idx = t; idx < 4096; idx += 256) {
            int o = idx >> 6, i = idx & 63;
            wkl[o][i] = dcn_w[((size_t)(g * 64 + o) * 64 + i) * 9 + k];
        }
        const int ky = k / 3, kx = k % 3;
        for (int sbi = 0; sbi < 2; ++sbi) {
            const int sb = b + sbi * 4;
            __syncthreads();  // wkl staged / previous GEMM done
            if (t < 64) {
                int ww = t;
                size_t obase = FUSED_SZ + (sb < 4 ? 0 : OFF_SZ)
                             + (size_t)(sb & 3) * 72 * HW
                             + (size_t)(g * 18 + k * 2) * HW + h * 64 + ww;
                float oy = dout[obase];
                float ox = dout[obase + HW];
                float m  = mask_ws[(size_t)sb * 36 * HW + (size_t)(g * 9 + k) * HW + h * 64 + ww];
                float py = oy + (float)(h - 1 + ky);
                float px = ox + (float)(ww - 1 + kx);
                float y0f = floorf(py), x0f = floorf(px);
                float fy = py - y0f, fx = px - x0f;
                int y0 = (int)y0f, x0 = (int)x0f;
                #pragma unroll
                for (int tap = 0; tap < 4; ++tap) {
                    int yy = y0 + (tap >> 1);
                    int xx = x0 + (tap & 1);
                    float wy = (tap >> 1) ? fy : 1.f - fy;
                    float wx = (tap & 1) ? fx : 1.f - fx;
                    bool valid = (yy >= 0 && yy < 64 && xx >= 0 && xx < 64);
                    int yc = min(max(yy, 0), 63), xc = min(max(xx, 0), 63);
                    cw[tap][ww]   = valid ? wy * wx * m : 0.f;
                    cidx[tap][ww] = yc * 64 + xc;
                }
            }
            __syncthreads();  // coords visible
            const float* Vb = vbuf + (size_t)sb * 256 * HW + (size_t)(g * 64) * HW;
            for (int idx = t; idx < 4096; idx += 256) {
                int i = idx >> 6, ww = idx & 63;
                const float* vp = Vb + (size_t)i * HW;
                samp[i][ww] = cw[0][ww] * vp[cidx[0][ww]] + cw[1][ww] * vp[cidx[1][ww]]
                            + cw[2][ww] * vp[cidx[2][ww]] + cw[3][ww] * vp[cidx[3][ww]];
            }
            __syncthreads();  // samp visible
            #pragma unroll
            for (int i = 0; i < 64; i += 4) {
                float sv0 = samp[i + 0][w], sv1 = samp[i + 1][w];
                float sv2 = samp[i + 2][w], sv3 = samp[i + 3][w];
                #pragma unroll
                for (int j = 0; j < 16; ++j) {
                    const float4 wv4 = *(const float4*)&wkl[og * 16 + j][i];
                    acc[j] += sv0 * wv4.x + sv1 * wv4.y + sv2 * wv4.z + sv3 * wv4.w;
                }
            }
        }
    }
    const float gm = gamma[0];
    #pragma unroll
    for (int j = 0; j < 16; ++j) {
        int o = g * 64 + og * 16 + j;
        size_t addr = (size_t)b * 256 * HW + (size_t)o * HW + h * 64 + w;
        dout[addr] = rife[addr] + gm * acc[j];
    }
}

// ---------------------------------------------------------------------------
extern "C" void kernel_launch(void* const* d_in, const int* in_sizes, int n_in,
                              void* d_out, int out_size, void* d_ws, size_t ws_size,
                              hipStream_t stream)
{
    const float* rife  = (const float*)d_in[0];
    const float* d0    = (const float*)d_in[1];
    const float* d1    = (const float*)d_in[2];
    const float* wq    = (const float*)d_in[3];
    const float* bq    = (const float*)d_in[4];
    const float* wk    = (const float*)d_in[5];
    const float* bk    = (const float*)d_in[6];
    const float* wv    = (const float*)d_in[7];
    const float* bv    = (const float*)d_in[8];
    const float* w_off = (const float*)d_in[9];
    const float* b_off = (const float*)d_in[10];
    const float* dcnw  = (const float*)d_in[11];
    const float* gamma = (const float*)d_in[12];
    float* out = (float*)d_out;
    float* ws  = (float*)d_ws;

    float* comb = ws;                         // 8*512*4096 f
    float* vbuf = ws + COMB_SZ;               // 8*256*4096 f
    float* mws  = ws + COMB_SZ + VBUF_SZ;     // 8*36*4096 f
    // total ws need: ~105.4 MB

    qkv_gemm<<<dim3(64, 12, 8), 256, 0, stream>>>(rife, d0, d1, wq, bq, wk, bk, wv, bv, comb, vbuf);
    offconv<<<dim3(64, 8), 256, 0, stream>>>(comb, w_off, b_off, out, mws);
    dcn_fuse<<<dim3(64, 4, 4), 256, 0, stream>>>(rife, dcnw, gamma, vbuf, mws, out);
}

// Round 2
// 1112.933 us; speedup vs baseline: 2.8160x; 2.8160x over previous
//
#include <hip/hip_runtime.h>
#include <math.h>

#define HW   4096
#define CDIM 256

typedef float f32x4  __attribute__((ext_vector_type(4)));
typedef short short8 __attribute__((ext_vector_type(8)));

// d_out layout (float offsets)
#define FUSED_SZ (4ULL*256*HW)
#define OFF_SZ   (4ULL*72*HW)

static __device__ __forceinline__ unsigned short f2b(float f) {
    unsigned u = __float_as_uint(f);
    unsigned r = (u + 0x7fffu + ((u >> 16) & 1u)) >> 16;
    return (unsigned short)r;
}

// ---------------------------------------------------------------------------
// Kernel 0: one-time weight transpose  w_off[108][512][9] f32
//   -> wT2[kk][o(pad 128)][c] bf16   (1.18 MB, L2-resident)
// ---------------------------------------------------------------------------
__global__ __launch_bounds__(256) void wprep(const float* __restrict__ w_off,
                                             unsigned short* __restrict__ wT2)
{
    int idx = blockIdx.x * 256 + threadIdx.x;
    if (idx >= 9 * 128 * 512) return;
    int kk  = idx / (128 * 512);
    int rem = idx - kk * 128 * 512;
    int o = rem >> 9;
    int c = rem & 511;
    float v = (o < 108) ? w_off[((size_t)o * 512 + c) * 9 + kk] : 0.f;
    wT2[idx] = f2b(v);
}

// ---------------------------------------------------------------------------
// Kernel 1: QKV 1x1 convs as tiled GEMM.
//   o0 < 512  -> comb_t  bf16 NHWC [s][pix][512]  (LDS-transpose epilogue)
//   o0 >= 512 -> vbuf    f32  NCHW (unchanged, feeds bilinear gather)
// ---------------------------------------------------------------------------
__global__ __launch_bounds__(256) void qkv_gemm(
    const float* __restrict__ rife, const float* __restrict__ d0, const float* __restrict__ d1,
    const float* __restrict__ wq, const float* __restrict__ bq,
    const float* __restrict__ wk, const float* __restrict__ bk,
    const float* __restrict__ wv, const float* __restrict__ bv,
    unsigned short* __restrict__ comb_t, float* __restrict__ vbuf)
{
    const int s    = blockIdx.z;
    const int o0   = blockIdx.y * 64;
    const int pix0 = blockIdx.x * 64;
    const int t    = threadIdx.x;

    const float* dsrc = (s < 4 ? d0 : d1) + (size_t)(s & 3) * CDIM * HW;
    const float* X; const float* Wm; const float* bias;
    if (o0 < 256) {
        X = rife + (size_t)(s & 3) * CDIM * HW;
        Wm = wq + (size_t)o0 * CDIM; bias = bq + o0;
    } else if (o0 < 512) {
        X = dsrc;
        Wm = wk + (size_t)(o0 - 256) * CDIM; bias = bk + (o0 - 256);
    } else {
        X = dsrc;
        Wm = wv + (size_t)(o0 - 512) * CDIM; bias = bv + (o0 - 512);
    }

    __shared__ float Xs[16][64];
    __shared__ float Wls[64][17];
    __shared__ float trs[64][65];

    const int tx = t & 15, ty = t >> 4;
    float acc[4][4] = {};

    for (int c0 = 0; c0 < 256; c0 += 16) {
        #pragma unroll
        for (int r = 0; r < 4; ++r) {
            int idx = t + r * 256;
            int kc = idx >> 6, pp = idx & 63;
            Xs[kc][pp] = X[(size_t)(c0 + kc) * HW + pix0 + pp];
        }
        #pragma unroll
        for (int r = 0; r < 4; ++r) {
            int idx = t + r * 256;
            int oo = idx >> 4, kc = idx & 15;
            Wls[oo][kc] = Wm[(size_t)oo * CDIM + c0 + kc];
        }
        __syncthreads();
        #pragma unroll
        for (int kc = 0; kc < 16; ++kc) {
            float a[4], bb[4];
            #pragma unroll
            for (int mi = 0; mi < 4; ++mi) a[mi] = Wls[ty * 4 + mi][kc];
            #pragma unroll
            for (int ni = 0; ni < 4; ++ni) bb[ni] = Xs[kc][tx * 4 + ni];
            #pragma unroll
            for (int mi = 0; mi < 4; ++mi)
                #pragma unroll
                for (int ni = 0; ni < 4; ++ni)
                    acc[mi][ni] += a[mi] * bb[ni];
        }
        __syncthreads();
    }

    if (o0 < 512) {
        // transpose through LDS, write bf16 NHWC (coalesced 16B stores)
        #pragma unroll
        for (int mi = 0; mi < 4; ++mi) {
            float bz = bias[ty * 4 + mi];
            #pragma unroll
            for (int ni = 0; ni < 4; ++ni)
                trs[tx * 4 + ni][ty * 4 + mi] = acc[mi][ni] + bz;
        }
        __syncthreads();
        const int pix = t >> 2, cq = t & 3;
        uint4 p0, p1;
        const float* row = &trs[pix][cq * 16];
        p0.x = (unsigned)f2b(row[0])  | ((unsigned)f2b(row[1])  << 16);
        p0.y = (unsigned)f2b(row[2])  | ((unsigned)f2b(row[3])  << 16);
        p0.z = (unsigned)f2b(row[4])  | ((unsigned)f2b(row[5])  << 16);
        p0.w = (unsigned)f2b(row[6])  | ((unsigned)f2b(row[7])  << 16);
        p1.x = (unsigned)f2b(row[8])  | ((unsigned)f2b(row[9])  << 16);
        p1.y = (unsigned)f2b(row[10]) | ((unsigned)f2b(row[11]) << 16);
        p1.z = (unsigned)f2b(row[12]) | ((unsigned)f2b(row[13]) << 16);
        p1.w = (unsigned)f2b(row[14]) | ((unsigned)f2b(row[15]) << 16);
        unsigned short* dst = comb_t + ((size_t)s * 4096 + pix0 + pix) * 512 + o0 + cq * 16;
        *(uint4*)dst = p0;
        *(uint4*)(dst + 8) = p1;
    } else {
        float* outp = vbuf + (size_t)s * 256 * HW + (size_t)(o0 - 512) * HW;
        #pragma unroll
        for (int mi = 0; mi < 4; ++mi) {
            float bz = bias[ty * 4 + mi];
            float4 v = make_float4(acc[mi][0] + bz, acc[mi][1] + bz,
                                   acc[mi][2] + bz, acc[mi][3] + bz);
            *(float4*)(outp + (size_t)(ty * 4 + mi) * HW + pix0 + tx * 4) = v;
        }
    }
}

// ---------------------------------------------------------------------------
// Kernel 2: 3x3 conv 512->108 as implicit GEMM on MFMA bf16.
// Block=(h,s), 4 waves. M=128 (pad of 108): 2 frags/wave; N=64 pixels: 4 frags.
// Per 32-ch slab: stage halo tile [3*66][32] bf16 in LDS; 9 taps * 8 MFMA.
// ---------------------------------------------------------------------------
__global__ __launch_bounds__(256) void offconv_mfma(
    const unsigned short* __restrict__ comb_t,
    const unsigned short* __restrict__ wT2,
    const float* __restrict__ b_off,
    float* __restrict__ dout, float* __restrict__ mask_ws)
{
    const int h = blockIdx.x;
    const int s = blockIdx.y;
    const int t = threadIdx.x;
    const int lane = t & 63;
    const int wid  = t >> 6;
    const int q    = lane >> 4;
    const int rl   = lane & 15;

    __shared__ __align__(16) unsigned short tb[198 * 32];

    const short8* cbv = (const short8*)comb_t + (size_t)s * 4096 * 64; // 64 short8 per pixel
    const short8* wv  = (const short8*)wT2;

    f32x4 acc[2][4];
    #pragma unroll
    for (int ma = 0; ma < 2; ++ma)
        #pragma unroll
        for (int nf = 0; nf < 4; ++nf)
            acc[ma][nf] = (f32x4){0.f, 0.f, 0.f, 0.f};

    for (int c0 = 0; c0 < 512; c0 += 32) {
        const int c8 = c0 >> 3;
        // hoist A-frags for this slab (L2-resident wT2); issue before staging
        short8 a[2][9];
        #pragma unroll
        for (int ma = 0; ma < 2; ++ma) {
            const int o = (wid * 2 + ma) * 16 + rl;
            #pragma unroll
            for (int kk = 0; kk < 9; ++kk)
                a[ma][kk] = wv[(size_t)(kk * 128 + o) * 64 + c8 + q];
        }
        __syncthreads();   // previous slab's tb readers done
        for (int idx = t; idx < 792; idx += 256) {
            int x = idx >> 2, cq = idx & 3;
            int ky = x / 66, xx = x - ky * 66;
            int hh = h + ky - 1, gx = xx - 1;
            short8 v = {0, 0, 0, 0, 0, 0, 0, 0};
            if (hh >= 0 && hh < 64 && gx >= 0 && gx < 64)
                v = cbv[(size_t)(hh * 64 + gx) * 64 + c8 + cq];
            *((short8*)tb + x * 4 + cq) = v;
        }
        __syncthreads();
        #pragma unroll
        for (int kk = 0; kk < 9; ++kk) {
            const int ky = kk / 3, kx = kk % 3;
            #pragma unroll
            for (int nf = 0; nf < 4; ++nf) {
                short8 b = *((const short8*)tb + (ky * 66 + nf * 16 + rl + kx) * 4 + q);
                acc[0][nf] = __builtin_amdgcn_mfma_f32_16x16x32_bf16(a[0][kk], b, acc[0][nf], 0, 0, 0);
                acc[1][nf] = __builtin_amdgcn_mfma_f32_16x16x32_bf16(a[1][kk], b, acc[1][nf], 0, 0, 0);
            }
        }
    }

    // epilogue: D row = o = mfrag*16 + q*4 + r ; col = pixel = nf*16 + rl
    const size_t obase = FUSED_SZ + (s < 4 ? 0 : OFF_SZ) + (size_t)(s & 3) * 72 * HW + (size_t)h * 64;
    const size_t mbase = (size_t)s * 36 * HW + (size_t)h * 64;
    #pragma unroll
    for (int ma = 0; ma < 2; ++ma) {
        #pragma unroll
        for (int r = 0; r < 4; ++r) {
            const int o = (wid * 2 + ma) * 16 + q * 4 + r;
            if (o >= 108) continue;
            const float bz = b_off[o];
            #pragma unroll
            for (int nf = 0; nf < 4; ++nf) {
                const int w = nf * 16 + rl;
                float v = acc[ma][nf][r] + bz;
                if (o < 72)
                    dout[obase + (size_t)o * HW + w] = v;
                else
                    mask_ws[mbase + (size_t)(o - 72) * HW + w] = 1.f / (1.f + expf(-v));
            }
        }
    }
}

// ---------------------------------------------------------------------------
// Kernel 3: deformable conv + residual fuse (unchanged fp32 this round).
// ---------------------------------------------------------------------------
__global__ __launch_bounds__(256) void dcn_fuse(
    const float* __restrict__ rife, const float* __restrict__ dcn_w,
    const float* __restrict__ gamma,
    const float* __restrict__ vbuf, const float* __restrict__ mask_ws,
    float* __restrict__ dout)
{
    const int h = blockIdx.x;
    const int g = blockIdx.y;
    const int b = blockIdx.z;
    const int t = threadIdx.x;
    const int w = t & 63;
    const int og = t >> 6;

    __shared__ __align__(16) float samp[64][64];
    __shared__ __align__(16) float wkl[64][64];
    __shared__ float cw[4][64];
    __shared__ int   cidx[4][64];

    float acc[16] = {};

    for (int k = 0; k < 9; ++k) {
        __syncthreads();
        for (int idx = t; idx < 4096; idx += 256) {
            int o = idx >> 6, i = idx & 63;
            wkl[o][i] = dcn_w[((size_t)(g * 64 + o) * 64 + i) * 9 + k];
        }
        const int ky = k / 3, kx = k % 3;
        for (int sbi = 0; sbi < 2; ++sbi) {
            const int sb = b + sbi * 4;
            __syncthreads();
            if (t < 64) {
                int ww = t;
                size_t obase = FUSED_SZ + (sb < 4 ? 0 : OFF_SZ)
                             + (size_t)(sb & 3) * 72 * HW
                             + (size_t)(g * 18 + k * 2) * HW + h * 64 + ww;
                float oy = dout[obase];
                float ox = dout[obase + HW];
                float m  = mask_ws[(size_t)sb * 36 * HW + (size_t)(g * 9 + k) * HW + h * 64 + ww];
                float py = oy + (float)(h - 1 + ky);
                float px = ox + (float)(ww - 1 + kx);
                float y0f = floorf(py), x0f = floorf(px);
                float fy = py - y0f, fx = px - x0f;
                int y0 = (int)y0f, x0 = (int)x0f;
                #pragma unroll
                for (int tap = 0; tap < 4; ++tap) {
                    int yy = y0 + (tap >> 1);
                    int xx = x0 + (tap & 1);
                    float wy = (tap >> 1) ? fy : 1.f - fy;
                    float wx = (tap & 1) ? fx : 1.f - fx;
                    bool valid = (yy >= 0 && yy < 64 && xx >= 0 && xx < 64);
                    int yc = min(max(yy, 0), 63), xc = min(max(xx, 0), 63);
                    cw[tap][ww]   = valid ? wy * wx * m : 0.f;
                    cidx[tap][ww] = yc * 64 + xc;
                }
            }
            __syncthreads();
            const float* Vb = vbuf + (size_t)sb * 256 * HW + (size_t)(g * 64) * HW;
            for (int idx = t; idx < 4096; idx += 256) {
                int i = idx >> 6, ww = idx & 63;
                const float* vp = Vb + (size_t)i * HW;
                samp[i][ww] = cw[0][ww] * vp[cidx[0][ww]] + cw[1][ww] * vp[cidx[1][ww]]
                            + cw[2][ww] * vp[cidx[2][ww]] + cw[3][ww] * vp[cidx[3][ww]];
            }
            __syncthreads();
            #pragma unroll
            for (int i = 0; i < 64; i += 4) {
                float sv0 = samp[i + 0][w], sv1 = samp[i + 1][w];
                float sv2 = samp[i + 2][w], sv3 = samp[i + 3][w];
                #pragma unroll
                for (int j = 0; j < 16; ++j) {
                    const float4 wv4 = *(const float4*)&wkl[og * 16 + j][i];
                    acc[j] += sv0 * wv4.x + sv1 * wv4.y + sv2 * wv4.z + sv3 * wv4.w;
                }
            }
        }
    }
    const float gm = gamma[0];
    #pragma unroll
    for (int j = 0; j < 16; ++j) {
        int o = g * 64 + og * 16 + j;
        size_t addr = (size_t)b * 256 * HW + (size_t)o * HW + h * 64 + w;
        dout[addr] = rife[addr] + gm * acc[j];
    }
}

// ---------------------------------------------------------------------------
extern "C" void kernel_launch(void* const* d_in, const int* in_sizes, int n_in,
                              void* d_out, int out_size, void* d_ws, size_t ws_size,
                              hipStream_t stream)
{
    const float* rife  = (const float*)d_in[0];
    const float* d0    = (const float*)d_in[1];
    const float* d1    = (const float*)d_in[2];
    const float* wq    = (const float*)d_in[3];
    const float* bq    = (const float*)d_in[4];
    const float* wk    = (const float*)d_in[5];
    const float* bk    = (const float*)d_in[6];
    const float* wv    = (const float*)d_in[7];
    const float* bv    = (const float*)d_in[8];
    const float* w_off = (const float*)d_in[9];
    const float* b_off = (const float*)d_in[10];
    const float* dcnw  = (const float*)d_in[11];
    const float* gamma = (const float*)d_in[12];
    float* out = (float*)d_out;
    char* wsb  = (char*)d_ws;

    // ws layout (bytes)
    unsigned short* comb_t = (unsigned short*)(wsb);              // 33,554,432
    float*          vbuf   = (float*)(wsb + 33554432);            // 33,554,432
    float*          mws    = (float*)(wsb + 67108864);            //  4,718,592
    unsigned short* wT2    = (unsigned short*)(wsb + 71827456);   //  1,179,648
    // total: ~73.0 MB

    wprep<<<2304, 256, 0, stream>>>(w_off, wT2);
    qkv_gemm<<<dim3(64, 12, 8), 256, 0, stream>>>(rife, d0, d1, wq, bq, wk, bk, wv, bv, comb_t, vbuf);
    offconv_mfma<<<dim3(64, 8), 256, 0, stream>>>(comb_t, wT2, b_off, out, mws);
    dcn_fuse<<<dim3(64, 4, 4), 256, 0, stream>>>(rife, dcnw, gamma, vbuf, mws, out);
}

// Round 3
// 662.639 us; speedup vs baseline: 4.7295x; 1.6795x over previous
//
#include <hip/hip_runtime.h>
#include <math.h>

#define HW   4096
#define CDIM 256

typedef float f32x4  __attribute__((ext_vector_type(4)));
typedef short short8 __attribute__((ext_vector_type(8)));

// d_out layout (float offsets)
#define FUSED_SZ (4ULL*256*HW)
#define OFF_SZ   (4ULL*72*HW)

static __device__ __forceinline__ unsigned short f2b(float f) {
    unsigned u = __float_as_uint(f);
    unsigned r = (u + 0x7fffu + ((u >> 16) & 1u)) >> 16;
    return (unsigned short)r;
}

// ---------------------------------------------------------------------------
// Kernel 0a: one-time weight transpose  w_off[108][512][9] f32
//   -> wT2[kk][o(pad 128)][c] bf16   (1.18 MB, L2-resident)
// ---------------------------------------------------------------------------
__global__ __launch_bounds__(256) void wprep(const float* __restrict__ w_off,
                                             unsigned short* __restrict__ wT2)
{
    int idx = blockIdx.x * 256 + threadIdx.x;
    if (idx >= 9 * 128 * 512) return;
    int kk  = idx / (128 * 512);
    int rem = idx - kk * 128 * 512;
    int o = rem >> 9;
    int c = rem & 511;
    float v = (o < 108) ? w_off[((size_t)o * 512 + c) * 9 + kk] : 0.f;
    wT2[idx] = f2b(v);
}

// ---------------------------------------------------------------------------
// Kernel 0b: one-time transpose  dcn_w[256][64][3][3] f32 -> dcnwT[k][o][i] bf16
// (294 KB, L2-resident; A-fragments become contiguous 16B loads)
// ---------------------------------------------------------------------------
__global__ __launch_bounds__(256) void dprep(const float* __restrict__ dcn_w,
                                             unsigned short* __restrict__ dcnwT)
{
    int idx = blockIdx.x * 256 + threadIdx.x;
    if (idx >= 9 * 256 * 64) return;
    int k   = idx / (256 * 64);
    int rem = idx - k * 256 * 64;
    int o = rem >> 6;
    int i = rem & 63;
    dcnwT[idx] = f2b(dcn_w[((size_t)o * 64 + i) * 9 + k]);
}

// ---------------------------------------------------------------------------
// Kernel 1: QKV 1x1 convs as tiled GEMM.
//   o0 < 512  -> comb_t  bf16 NHWC [s][pix][512]  (LDS-transpose epilogue)
//   o0 >= 512 -> vbuf    f32  NCHW (feeds bilinear gather)
// ---------------------------------------------------------------------------
__global__ __launch_bounds__(256) void qkv_gemm(
    const float* __restrict__ rife, const float* __restrict__ d0, const float* __restrict__ d1,
    const float* __restrict__ wq, const float* __restrict__ bq,
    const float* __restrict__ wk, const float* __restrict__ bk,
    const float* __restrict__ wv, const float* __restrict__ bv,
    unsigned short* __restrict__ comb_t, float* __restrict__ vbuf)
{
    const int s    = blockIdx.z;
    const int o0   = blockIdx.y * 64;
    const int pix0 = blockIdx.x * 64;
    const int t    = threadIdx.x;

    const float* dsrc = (s < 4 ? d0 : d1) + (size_t)(s & 3) * CDIM * HW;
    const float* X; const float* Wm; const float* bias;
    if (o0 < 256) {
        X = rife + (size_t)(s & 3) * CDIM * HW;
        Wm = wq + (size_t)o0 * CDIM; bias = bq + o0;
    } else if (o0 < 512) {
        X = dsrc;
        Wm = wk + (size_t)(o0 - 256) * CDIM; bias = bk + (o0 - 256);
    } else {
        X = dsrc;
        Wm = wv + (size_t)(o0 - 512) * CDIM; bias = bv + (o0 - 512);
    }

    __shared__ float Xs[16][64];
    __shared__ float Wls[64][17];
    __shared__ float trs[64][65];

    const int tx = t & 15, ty = t >> 4;
    float acc[4][4] = {};

    for (int c0 = 0; c0 < 256; c0 += 16) {
        #pragma unroll
        for (int r = 0; r < 4; ++r) {
            int idx = t + r * 256;
            int kc = idx >> 6, pp = idx & 63;
            Xs[kc][pp] = X[(size_t)(c0 + kc) * HW + pix0 + pp];
        }
        #pragma unroll
        for (int r = 0; r < 4; ++r) {
            int idx = t + r * 256;
            int oo = idx >> 4, kc = idx & 15;
            Wls[oo][kc] = Wm[(size_t)oo * CDIM + c0 + kc];
        }
        __syncthreads();
        #pragma unroll
        for (int kc = 0; kc < 16; ++kc) {
            float a[4], bb[4];
            #pragma unroll
            for (int mi = 0; mi < 4; ++mi) a[mi] = Wls[ty * 4 + mi][kc];
            #pragma unroll
            for (int ni = 0; ni < 4; ++ni) bb[ni] = Xs[kc][tx * 4 + ni];
            #pragma unroll
            for (int mi = 0; mi < 4; ++mi)
                #pragma unroll
                for (int ni = 0; ni < 4; ++ni)
                    acc[mi][ni] += a[mi] * bb[ni];
        }
        __syncthreads();
    }

    if (o0 < 512) {
        #pragma unroll
        for (int mi = 0; mi < 4; ++mi) {
            float bz = bias[ty * 4 + mi];
            #pragma unroll
            for (int ni = 0; ni < 4; ++ni)
                trs[tx * 4 + ni][ty * 4 + mi] = acc[mi][ni] + bz;
        }
        __syncthreads();
        const int pix = t >> 2, cq = t & 3;
        uint4 p0, p1;
        const float* row = &trs[pix][cq * 16];
        p0.x = (unsigned)f2b(row[0])  | ((unsigned)f2b(row[1])  << 16);
        p0.y = (unsigned)f2b(row[2])  | ((unsigned)f2b(row[3])  << 16);
        p0.z = (unsigned)f2b(row[4])  | ((unsigned)f2b(row[5])  << 16);
        p0.w = (unsigned)f2b(row[6])  | ((unsigned)f2b(row[7])  << 16);
        p1.x = (unsigned)f2b(row[8])  | ((unsigned)f2b(row[9])  << 16);
        p1.y = (unsigned)f2b(row[10]) | ((unsigned)f2b(row[11]) << 16);
        p1.z = (unsigned)f2b(row[12]) | ((unsigned)f2b(row[13]) << 16);
        p1.w = (unsigned)f2b(row[14]) | ((unsigned)f2b(row[15]) << 16);
        unsigned short* dst = comb_t + ((size_t)s * 4096 + pix0 + pix) * 512 + o0 + cq * 16;
        *(uint4*)dst = p0;
        *(uint4*)(dst + 8) = p1;
    } else {
        float* outp = vbuf + (size_t)s * 256 * HW + (size_t)(o0 - 512) * HW;
        #pragma unroll
        for (int mi = 0; mi < 4; ++mi) {
            float bz = bias[ty * 4 + mi];
            float4 v = make_float4(acc[mi][0] + bz, acc[mi][1] + bz,
                                   acc[mi][2] + bz, acc[mi][3] + bz);
            *(float4*)(outp + (size_t)(ty * 4 + mi) * HW + pix0 + tx * 4) = v;
        }
    }
}

// ---------------------------------------------------------------------------
// Kernel 2: 3x3 conv 512->108 as implicit GEMM on MFMA bf16.
// ---------------------------------------------------------------------------
__global__ __launch_bounds__(256) void offconv_mfma(
    const unsigned short* __restrict__ comb_t,
    const unsigned short* __restrict__ wT2,
    const float* __restrict__ b_off,
    float* __restrict__ dout, float* __restrict__ mask_ws)
{
    const int h = blockIdx.x;
    const int s = blockIdx.y;
    const int t = threadIdx.x;
    const int lane = t & 63;
    const int wid  = t >> 6;
    const int q    = lane >> 4;
    const int rl   = lane & 15;

    __shared__ __align__(16) unsigned short tb[198 * 32];

    const short8* cbv = (const short8*)comb_t + (size_t)s * 4096 * 64;
    const short8* wv  = (const short8*)wT2;

    f32x4 acc[2][4];
    #pragma unroll
    for (int ma = 0; ma < 2; ++ma)
        #pragma unroll
        for (int nf = 0; nf < 4; ++nf)
            acc[ma][nf] = (f32x4){0.f, 0.f, 0.f, 0.f};

    for (int c0 = 0; c0 < 512; c0 += 32) {
        const int c8 = c0 >> 3;
        short8 a[2][9];
        #pragma unroll
        for (int ma = 0; ma < 2; ++ma) {
            const int o = (wid * 2 + ma) * 16 + rl;
            #pragma unroll
            for (int kk = 0; kk < 9; ++kk)
                a[ma][kk] = wv[(size_t)(kk * 128 + o) * 64 + c8 + q];
        }
        __syncthreads();
        for (int idx = t; idx < 792; idx += 256) {
            int x = idx >> 2, cq = idx & 3;
            int ky = x / 66, xx = x - ky * 66;
            int hh = h + ky - 1, gx = xx - 1;
            short8 v = {0, 0, 0, 0, 0, 0, 0, 0};
            if (hh >= 0 && hh < 64 && gx >= 0 && gx < 64)
                v = cbv[(size_t)(hh * 64 + gx) * 64 + c8 + cq];
            *((short8*)tb + x * 4 + cq) = v;
        }
        __syncthreads();
        #pragma unroll
        for (int kk = 0; kk < 9; ++kk) {
            const int ky = kk / 3, kx = kk % 3;
            #pragma unroll
            for (int nf = 0; nf < 4; ++nf) {
                short8 b = *((const short8*)tb + (ky * 66 + nf * 16 + rl + kx) * 4 + q);
                acc[0][nf] = __builtin_amdgcn_mfma_f32_16x16x32_bf16(a[0][kk], b, acc[0][nf], 0, 0, 0);
                acc[1][nf] = __builtin_amdgcn_mfma_f32_16x16x32_bf16(a[1][kk], b, acc[1][nf], 0, 0, 0);
            }
        }
    }

    const size_t obase = FUSED_SZ + (s < 4 ? 0 : OFF_SZ) + (size_t)(s & 3) * 72 * HW + (size_t)h * 64;
    const size_t mbase = (size_t)s * 36 * HW + (size_t)h * 64;
    #pragma unroll
    for (int ma = 0; ma < 2; ++ma) {
        #pragma unroll
        for (int r = 0; r < 4; ++r) {
            const int o = (wid * 2 + ma) * 16 + q * 4 + r;
            if (o >= 108) continue;
            const float bz = b_off[o];
            #pragma unroll
            for (int nf = 0; nf < 4; ++nf) {
                const int w = nf * 16 + rl;
                float v = acc[ma][nf][r] + bz;
                if (o < 72)
                    dout[obase + (size_t)o * HW + w] = v;
                else
                    mask_ws[mbase + (size_t)(o - 72) * HW + w] = 1.f / (1.f + expf(-v));
            }
        }
    }
}

// ---------------------------------------------------------------------------
// Kernel 3: deformable conv + residual fuse, MFMA bf16, zero LDS / barriers.
// Block = 4 waves; wave owns 64o x 16pix tile of one (b,g,h) row.
// K-chain = 2 sb * 9 taps * 64 ch -> one accumulator (a0+a1 folded).
// B-fragments (bilinear samples) built in registers; A from L2-resident dcnwT.
// Grid: bid = h*16 + (b*4+g)  => all h-rows of a combo on one XCD (L2 local).
// ---------------------------------------------------------------------------
__global__ __launch_bounds__(256) void dcn_fuse_mfma(
    const float* __restrict__ rife, const unsigned short* __restrict__ dcnwT,
    const float* __restrict__ gamma,
    const float* __restrict__ vbuf, const float* __restrict__ mask_ws,
    float* __restrict__ dout)
{
    const int bid = blockIdx.x;
    const int c   = bid & 15;
    const int h   = bid >> 4;
    const int b   = c >> 2;
    const int g   = c & 3;
    const int t    = threadIdx.x;
    const int wv   = t >> 6;
    const int lane = t & 63;
    const int q    = lane >> 4;
    const int rl   = lane & 15;
    const int pix  = wv * 16 + rl;

    const short8* aT = (const short8*)dcnwT;

    f32x4 acc[4];
    #pragma unroll
    for (int ma = 0; ma < 4; ++ma) acc[ma] = (f32x4){0.f, 0.f, 0.f, 0.f};

    for (int k = 0; k < 9; ++k) {
        const int ky = k / 3, kx = k % 3;
        // A-fragments for this tap (shared across both sb)
        short8 a[4][2];
        #pragma unroll
        for (int ma = 0; ma < 4; ++ma)
            #pragma unroll
            for (int ks = 0; ks < 2; ++ks)
                a[ma][ks] = aT[(size_t)(k * 256 + g * 64 + ma * 16 + rl) * 8 + ks * 4 + q];

        #pragma unroll
        for (int sbi = 0; sbi < 2; ++sbi) {
            const int sb = b + sbi * 4;
            // per-pixel coords (q-groups duplicate; cheap)
            const size_t obase = FUSED_SZ + (sb < 4 ? 0 : OFF_SZ)
                               + (size_t)(sb & 3) * 72 * HW
                               + (size_t)(g * 18 + k * 2) * HW + (size_t)h * 64 + pix;
            const float oy = dout[obase];
            const float ox = dout[obase + HW];
            const float m  = mask_ws[(size_t)sb * 36 * HW + (size_t)(g * 9 + k) * HW + (size_t)h * 64 + pix];

            const float py = oy + (float)(h - 1 + ky);
            const float px = ox + (float)(pix - 1 + kx);
            const float y0f = floorf(py), x0f = floorf(px);
            const float fy = py - y0f, fx = px - x0f;
            const int y0 = (int)y0f, x0 = (int)x0f;
            const bool vy0 = (y0 >= 0) && (y0 < 64);
            const bool vy1 = (y0 >= -1) && (y0 < 63);
            const bool vx0 = (x0 >= 0) && (x0 < 64);
            const bool vx1 = (x0 >= -1) && (x0 < 63);
            const float w00 = (1.f - fy) * (1.f - fx) * m * (float)(vy0 && vx0);
            const float w01 = (1.f - fy) * fx        * m * (float)(vy0 && vx1);
            const float w10 = fy * (1.f - fx)        * m * (float)(vy1 && vx0);
            const float w11 = fy * fx                * m * (float)(vy1 && vx1);
            const int yc0 = min(max(y0, 0), 63),     yc1 = min(max(y0 + 1, 0), 63);
            const int xc0 = min(max(x0, 0), 63),     xc1 = min(max(x0 + 1, 0), 63);
            const int o00 = yc0 * 64 + xc0, o01 = yc0 * 64 + xc1;
            const int o10 = yc1 * 64 + xc0, o11 = yc1 * 64 + xc1;

            const float* Vb = vbuf + ((size_t)sb * 256 + g * 64) * HW;
            #pragma unroll
            for (int ks = 0; ks < 2; ++ks) {
                short8 bf;
                #pragma unroll
                for (int cc = 0; cc < 8; ++cc) {
                    const float* vp = Vb + (size_t)(q * 8 + cc + ks * 32) * HW;
                    float sres = w00 * vp[o00] + w01 * vp[o01]
                               + w10 * vp[o10] + w11 * vp[o11];
                    bf[cc] = (short)f2b(sres);
                }
                acc[0] = __builtin_amdgcn_mfma_f32_16x16x32_bf16(a[0][ks], bf, acc[0], 0, 0, 0);
                acc[1] = __builtin_amdgcn_mfma_f32_16x16x32_bf16(a[1][ks], bf, acc[1], 0, 0, 0);
                acc[2] = __builtin_amdgcn_mfma_f32_16x16x32_bf16(a[2][ks], bf, acc[2], 0, 0, 0);
                acc[3] = __builtin_amdgcn_mfma_f32_16x16x32_bf16(a[3][ks], bf, acc[3], 0, 0, 0);
            }
        }
    }

    const float gm = gamma[0];
    #pragma unroll
    for (int ma = 0; ma < 4; ++ma) {
        #pragma unroll
        for (int r = 0; r < 4; ++r) {
            const int o = g * 64 + ma * 16 + q * 4 + r;
            const size_t addr = ((size_t)b * 256 + o) * HW + (size_t)h * 64 + pix;
            dout[addr] = rife[addr] + gm * acc[ma][r];
        }
    }
}

// ---------------------------------------------------------------------------
extern "C" void kernel_launch(void* const* d_in, const int* in_sizes, int n_in,
                              void* d_out, int out_size, void* d_ws, size_t ws_size,
                              hipStream_t stream)
{
    const float* rife  = (const float*)d_in[0];
    const float* d0    = (const float*)d_in[1];
    const float* d1    = (const float*)d_in[2];
    const float* wq    = (const float*)d_in[3];
    const float* bq    = (const float*)d_in[4];
    const float* wk    = (const float*)d_in[5];
    const float* bk    = (const float*)d_in[6];
    const float* wv    = (const float*)d_in[7];
    const float* bv    = (const float*)d_in[8];
    const float* w_off = (const float*)d_in[9];
    const float* b_off = (const float*)d_in[10];
    const float* dcnw  = (const float*)d_in[11];
    const float* gamma = (const float*)d_in[12];
    float* out = (float*)d_out;
    char* wsb  = (char*)d_ws;

    // ws layout (bytes)
    unsigned short* comb_t = (unsigned short*)(wsb);              // 33,554,432
    float*          vbuf   = (float*)(wsb + 33554432);            // 33,554,432
    float*          mws    = (float*)(wsb + 67108864);            //  4,718,592
    unsigned short* wT2    = (unsigned short*)(wsb + 71827456);   //  1,179,648
    unsigned short* dcnwT  = (unsigned short*)(wsb + 73007104);   //    294,912
    // total: ~73.3 MB

    wprep<<<2304, 256, 0, stream>>>(w_off, wT2);
    dprep<<<576, 256, 0, stream>>>(dcnw, dcnwT);
    qkv_gemm<<<dim3(64, 12, 8), 256, 0, stream>>>(rife, d0, d1, wq, bq, wk, bk, wv, bv, comb_t, vbuf);
    offconv_mfma<<<dim3(64, 8), 256, 0, stream>>>(comb_t, wT2, b_off, out, mws);
    dcn_fuse_mfma<<<1024, 256, 0, stream>>>(rife, dcnwT, gamma, vbuf, mws, out);
}

// Round 4
// 422.494 us; speedup vs baseline: 7.4178x; 1.5684x over previous
//
#include <hip/hip_runtime.h>
#include <math.h>

#define HW   4096
#define CDIM 256

typedef float f32x4  __attribute__((ext_vector_type(4)));
typedef short short8 __attribute__((ext_vector_type(8)));

// d_out layout (float offsets)
#define FUSED_SZ (4ULL*256*HW)
#define OFF_SZ   (4ULL*72*HW)

static __device__ __forceinline__ unsigned short f2b(float f) {
    unsigned u = __float_as_uint(f);
    unsigned r = (u + 0x7fffu + ((u >> 16) & 1u)) >> 16;
    return (unsigned short)r;
}
static __device__ __forceinline__ float b2f(short h) {
    return __uint_as_float(((unsigned)(unsigned short)h) << 16);
}

// ---------------------------------------------------------------------------
// Kernel 0a: one-time weight transpose  w_off[108][512][9] f32
//   -> wT2[kk][o(pad 128)][c] bf16   (1.18 MB, L2-resident)
// ---------------------------------------------------------------------------
__global__ __launch_bounds__(256) void wprep(const float* __restrict__ w_off,
                                             unsigned short* __restrict__ wT2)
{
    int idx = blockIdx.x * 256 + threadIdx.x;
    if (idx >= 9 * 128 * 512) return;
    int kk  = idx / (128 * 512);
    int rem = idx - kk * 128 * 512;
    int o = rem >> 9;
    int c = rem & 511;
    float v = (o < 108) ? w_off[((size_t)o * 512 + c) * 9 + kk] : 0.f;
    wT2[idx] = f2b(v);
}

// ---------------------------------------------------------------------------
// Kernel 0b: one-time transpose  dcn_w[256][64][3][3] f32 -> dcnwT[k][o][i] bf16
// ---------------------------------------------------------------------------
__global__ __launch_bounds__(256) void dprep(const float* __restrict__ dcn_w,
                                             unsigned short* __restrict__ dcnwT)
{
    int idx = blockIdx.x * 256 + threadIdx.x;
    if (idx >= 9 * 256 * 64) return;
    int k   = idx / (256 * 64);
    int rem = idx - k * 256 * 64;
    int o = rem >> 6;
    int i = rem & 63;
    dcnwT[idx] = f2b(dcn_w[((size_t)o * 64 + i) * 9 + k]);
}

// ---------------------------------------------------------------------------
// Kernel 1: QKV 1x1 convs as tiled GEMM.
//   o0 < 512  -> comb_t  bf16 NHWC [s][pix][512]
//   o0 >= 512 -> vbuf_t  bf16 NHWC [s][pix][256]  (feeds vectorized gather)
// Both via LDS-transpose epilogue (coalesced 16B stores).
// ---------------------------------------------------------------------------
__global__ __launch_bounds__(256) void qkv_gemm(
    const float* __restrict__ rife, const float* __restrict__ d0, const float* __restrict__ d1,
    const float* __restrict__ wq, const float* __restrict__ bq,
    const float* __restrict__ wk, const float* __restrict__ bk,
    const float* __restrict__ wv, const float* __restrict__ bv,
    unsigned short* __restrict__ comb_t, unsigned short* __restrict__ vbuf_t)
{
    const int s    = blockIdx.z;
    const int o0   = blockIdx.y * 64;
    const int pix0 = blockIdx.x * 64;
    const int t    = threadIdx.x;

    const float* dsrc = (s < 4 ? d0 : d1) + (size_t)(s & 3) * CDIM * HW;
    const float* X; const float* Wm; const float* bias;
    if (o0 < 256) {
        X = rife + (size_t)(s & 3) * CDIM * HW;
        Wm = wq + (size_t)o0 * CDIM; bias = bq + o0;
    } else if (o0 < 512) {
        X = dsrc;
        Wm = wk + (size_t)(o0 - 256) * CDIM; bias = bk + (o0 - 256);
    } else {
        X = dsrc;
        Wm = wv + (size_t)(o0 - 512) * CDIM; bias = bv + (o0 - 512);
    }

    __shared__ float Xs[16][64];
    __shared__ float Wls[64][17];
    __shared__ float trs[64][65];

    const int tx = t & 15, ty = t >> 4;
    float acc[4][4] = {};

    for (int c0 = 0; c0 < 256; c0 += 16) {
        #pragma unroll
        for (int r = 0; r < 4; ++r) {
            int idx = t + r * 256;
            int kc = idx >> 6, pp = idx & 63;
            Xs[kc][pp] = X[(size_t)(c0 + kc) * HW + pix0 + pp];
        }
        #pragma unroll
        for (int r = 0; r < 4; ++r) {
            int idx = t + r * 256;
            int oo = idx >> 4, kc = idx & 15;
            Wls[oo][kc] = Wm[(size_t)oo * CDIM + c0 + kc];
        }
        __syncthreads();
        #pragma unroll
        for (int kc = 0; kc < 16; ++kc) {
            float a[4], bb[4];
            #pragma unroll
            for (int mi = 0; mi < 4; ++mi) a[mi] = Wls[ty * 4 + mi][kc];
            #pragma unroll
            for (int ni = 0; ni < 4; ++ni) bb[ni] = Xs[kc][tx * 4 + ni];
            #pragma unroll
            for (int mi = 0; mi < 4; ++mi)
                #pragma unroll
                for (int ni = 0; ni < 4; ++ni)
                    acc[mi][ni] += a[mi] * bb[ni];
        }
        __syncthreads();
    }

    // transpose through LDS, write bf16 NHWC (coalesced 16B stores)
    #pragma unroll
    for (int mi = 0; mi < 4; ++mi) {
        float bz = bias[ty * 4 + mi];
        #pragma unroll
        for (int ni = 0; ni < 4; ++ni)
            trs[tx * 4 + ni][ty * 4 + mi] = acc[mi][ni] + bz;
    }
    __syncthreads();
    const int pix = t >> 2, cq = t & 3;
    uint4 p0, p1;
    const float* row = &trs[pix][cq * 16];
    p0.x = (unsigned)f2b(row[0])  | ((unsigned)f2b(row[1])  << 16);
    p0.y = (unsigned)f2b(row[2])  | ((unsigned)f2b(row[3])  << 16);
    p0.z = (unsigned)f2b(row[4])  | ((unsigned)f2b(row[5])  << 16);
    p0.w = (unsigned)f2b(row[6])  | ((unsigned)f2b(row[7])  << 16);
    p1.x = (unsigned)f2b(row[8])  | ((unsigned)f2b(row[9])  << 16);
    p1.y = (unsigned)f2b(row[10]) | ((unsigned)f2b(row[11]) << 16);
    p1.z = (unsigned)f2b(row[12]) | ((unsigned)f2b(row[13]) << 16);
    p1.w = (unsigned)f2b(row[14]) | ((unsigned)f2b(row[15]) << 16);
    unsigned short* dst;
    if (o0 < 512)
        dst = comb_t + ((size_t)s * 4096 + pix0 + pix) * 512 + o0 + cq * 16;
    else
        dst = vbuf_t + ((size_t)s * 4096 + pix0 + pix) * 256 + (o0 - 512) + cq * 16;
    *(uint4*)dst = p0;
    *(uint4*)(dst + 8) = p1;
}

// ---------------------------------------------------------------------------
// Kernel 2: 3x3 conv 512->108 as implicit GEMM on MFMA bf16.
// ---------------------------------------------------------------------------
__global__ __launch_bounds__(256) void offconv_mfma(
    const unsigned short* __restrict__ comb_t,
    const unsigned short* __restrict__ wT2,
    const float* __restrict__ b_off,
    float* __restrict__ dout, float* __restrict__ mask_ws)
{
    const int h = blockIdx.x;
    const int s = blockIdx.y;
    const int t = threadIdx.x;
    const int lane = t & 63;
    const int wid  = t >> 6;
    const int q    = lane >> 4;
    const int rl   = lane & 15;

    __shared__ __align__(16) unsigned short tb[198 * 32];

    const short8* cbv = (const short8*)comb_t + (size_t)s * 4096 * 64;
    const short8* wv  = (const short8*)wT2;

    f32x4 acc[2][4];
    #pragma unroll
    for (int ma = 0; ma < 2; ++ma)
        #pragma unroll
        for (int nf = 0; nf < 4; ++nf)
            acc[ma][nf] = (f32x4){0.f, 0.f, 0.f, 0.f};

    for (int c0 = 0; c0 < 512; c0 += 32) {
        const int c8 = c0 >> 3;
        short8 a[2][9];
        #pragma unroll
        for (int ma = 0; ma < 2; ++ma) {
            const int o = (wid * 2 + ma) * 16 + rl;
            #pragma unroll
            for (int kk = 0; kk < 9; ++kk)
                a[ma][kk] = wv[(size_t)(kk * 128 + o) * 64 + c8 + q];
        }
        __syncthreads();
        for (int idx = t; idx < 792; idx += 256) {
            int x = idx >> 2, cq = idx & 3;
            int ky = x / 66, xx = x - ky * 66;
            int hh = h + ky - 1, gx = xx - 1;
            short8 v = {0, 0, 0, 0, 0, 0, 0, 0};
            if (hh >= 0 && hh < 64 && gx >= 0 && gx < 64)
                v = cbv[(size_t)(hh * 64 + gx) * 64 + c8 + cq];
            *((short8*)tb + x * 4 + cq) = v;
        }
        __syncthreads();
        #pragma unroll
        for (int kk = 0; kk < 9; ++kk) {
            const int ky = kk / 3, kx = kk % 3;
            #pragma unroll
            for (int nf = 0; nf < 4; ++nf) {
                short8 b = *((const short8*)tb + (ky * 66 + nf * 16 + rl + kx) * 4 + q);
                acc[0][nf] = __builtin_amdgcn_mfma_f32_16x16x32_bf16(a[0][kk], b, acc[0][nf], 0, 0, 0);
                acc[1][nf] = __builtin_amdgcn_mfma_f32_16x16x32_bf16(a[1][kk], b, acc[1][nf], 0, 0, 0);
            }
        }
    }

    const size_t obase = FUSED_SZ + (s < 4 ? 0 : OFF_SZ) + (size_t)(s & 3) * 72 * HW + (size_t)h * 64;
    const size_t mbase = (size_t)s * 36 * HW + (size_t)h * 64;
    #pragma unroll
    for (int ma = 0; ma < 2; ++ma) {
        #pragma unroll
        for (int r = 0; r < 4; ++r) {
            const int o = (wid * 2 + ma) * 16 + q * 4 + r;
            if (o >= 108) continue;
            const float bz = b_off[o];
            #pragma unroll
            for (int nf = 0; nf < 4; ++nf) {
                const int w = nf * 16 + rl;
                float v = acc[ma][nf][r] + bz;
                if (o < 72)
                    dout[obase + (size_t)o * HW + w] = v;
                else
                    mask_ws[mbase + (size_t)(o - 72) * HW + w] = 1.f / (1.f + expf(-v));
            }
        }
    }
}

// ---------------------------------------------------------------------------
// Kernel 3: deformable conv + residual fuse, MFMA bf16, zero LDS / barriers.
// Block = 4 waves; wave owns 64o x 16pix tile of one (b,g,h) row.
// B-fragments built from NHWC bf16 V: one 16B load per 8-channel corner.
// Grid: bid = h*16 + (b*4+g)  => all h-rows of a combo on one XCD (L2 local).
// ---------------------------------------------------------------------------
__global__ __launch_bounds__(256) void dcn_fuse_mfma(
    const float* __restrict__ rife, const unsigned short* __restrict__ dcnwT,
    const float* __restrict__ gamma,
    const unsigned short* __restrict__ vbuf_t, const float* __restrict__ mask_ws,
    float* __restrict__ dout)
{
    const int bid = blockIdx.x;
    const int c   = bid & 15;
    const int h   = bid >> 4;
    const int b   = c >> 2;
    const int g   = c & 3;
    const int t    = threadIdx.x;
    const int wv   = t >> 6;
    const int lane = t & 63;
    const int q    = lane >> 4;
    const int rl   = lane & 15;
    const int pix  = wv * 16 + rl;

    const short8* aT = (const short8*)dcnwT;

    f32x4 acc[4];
    #pragma unroll
    for (int ma = 0; ma < 4; ++ma) acc[ma] = (f32x4){0.f, 0.f, 0.f, 0.f};

    for (int k = 0; k < 9; ++k) {
        const int ky = k / 3, kx = k % 3;
        // A-fragments for this tap (shared across both sb)
        short8 a[4][2];
        #pragma unroll
        for (int ma = 0; ma < 4; ++ma)
            #pragma unroll
            for (int ks = 0; ks < 2; ++ks)
                a[ma][ks] = aT[(size_t)(k * 256 + g * 64 + ma * 16 + rl) * 8 + ks * 4 + q];

        #pragma unroll
        for (int sbi = 0; sbi < 2; ++sbi) {
            const int sb = b + sbi * 4;
            const size_t obase = FUSED_SZ + (sb < 4 ? 0 : OFF_SZ)
                               + (size_t)(sb & 3) * 72 * HW
                               + (size_t)(g * 18 + k * 2) * HW + (size_t)h * 64 + pix;
            const float oy = dout[obase];
            const float ox = dout[obase + HW];
            const float m  = mask_ws[(size_t)sb * 36 * HW + (size_t)(g * 9 + k) * HW + (size_t)h * 64 + pix];

            const float py = oy + (float)(h - 1 + ky);
            const float px = ox + (float)(pix - 1 + kx);
            const float y0f = floorf(py), x0f = floorf(px);
            const float fy = py - y0f, fx = px - x0f;
            const int y0 = (int)y0f, x0 = (int)x0f;
            const bool vy0 = (y0 >= 0) && (y0 < 64);
            const bool vy1 = (y0 >= -1) && (y0 < 63);
            const bool vx0 = (x0 >= 0) && (x0 < 64);
            const bool vx1 = (x0 >= -1) && (x0 < 63);
            const float w00 = (1.f - fy) * (1.f - fx) * m * (float)(vy0 && vx0);
            const float w01 = (1.f - fy) * fx        * m * (float)(vy0 && vx1);
            const float w10 = fy * (1.f - fx)        * m * (float)(vy1 && vx0);
            const float w11 = fy * fx                * m * (float)(vy1 && vx1);
            const int yc0 = min(max(y0, 0), 63),     yc1 = min(max(y0 + 1, 0), 63);
            const int xc0 = min(max(x0, 0), 63),     xc1 = min(max(x0 + 1, 0), 63);
            const size_t o00 = (size_t)(yc0 * 64 + xc0) * 256;
            const size_t o01 = (size_t)(yc0 * 64 + xc1) * 256;
            const size_t o10 = (size_t)(yc1 * 64 + xc0) * 256;
            const size_t o11 = (size_t)(yc1 * 64 + xc1) * 256;

            // NHWC bf16 V: channel base for this lane
            const unsigned short* Vb = vbuf_t + (size_t)sb * 4096 * 256 + g * 64 + q * 8;

            // issue all 8 16B loads (both ks) for MLP
            short8 v00a = *(const short8*)(Vb + o00);
            short8 v01a = *(const short8*)(Vb + o01);
            short8 v10a = *(const short8*)(Vb + o10);
            short8 v11a = *(const short8*)(Vb + o11);
            short8 v00b = *(const short8*)(Vb + o00 + 32);
            short8 v01b = *(const short8*)(Vb + o01 + 32);
            short8 v10b = *(const short8*)(Vb + o10 + 32);
            short8 v11b = *(const short8*)(Vb + o11 + 32);

            short8 bf0, bf1;
            #pragma unroll
            for (int cc = 0; cc < 8; ++cc) {
                float s0 = w00 * b2f(v00a[cc]) + w01 * b2f(v01a[cc])
                         + w10 * b2f(v10a[cc]) + w11 * b2f(v11a[cc]);
                float s1 = w00 * b2f(v00b[cc]) + w01 * b2f(v01b[cc])
                         + w10 * b2f(v10b[cc]) + w11 * b2f(v11b[cc]);
                bf0[cc] = (short)f2b(s0);
                bf1[cc] = (short)f2b(s1);
            }
            acc[0] = __builtin_amdgcn_mfma_f32_16x16x32_bf16(a[0][0], bf0, acc[0], 0, 0, 0);
            acc[1] = __builtin_amdgcn_mfma_f32_16x16x32_bf16(a[1][0], bf0, acc[1], 0, 0, 0);
            acc[2] = __builtin_amdgcn_mfma_f32_16x16x32_bf16(a[2][0], bf0, acc[2], 0, 0, 0);
            acc[3] = __builtin_amdgcn_mfma_f32_16x16x32_bf16(a[3][0], bf0, acc[3], 0, 0, 0);
            acc[0] = __builtin_amdgcn_mfma_f32_16x16x32_bf16(a[0][1], bf1, acc[0], 0, 0, 0);
            acc[1] = __builtin_amdgcn_mfma_f32_16x16x32_bf16(a[1][1], bf1, acc[1], 0, 0, 0);
            acc[2] = __builtin_amdgcn_mfma_f32_16x16x32_bf16(a[2][1], bf1, acc[2], 0, 0, 0);
            acc[3] = __builtin_amdgcn_mfma_f32_16x16x32_bf16(a[3][1], bf1, acc[3], 0, 0, 0);
        }
    }

    const float gm = gamma[0];
    #pragma unroll
    for (int ma = 0; ma < 4; ++ma) {
        #pragma unroll
        for (int r = 0; r < 4; ++r) {
            const int o = g * 64 + ma * 16 + q * 4 + r;
            const size_t addr = ((size_t)b * 256 + o) * HW + (size_t)h * 64 + pix;
            dout[addr] = rife[addr] + gm * acc[ma][r];
        }
    }
}

// ---------------------------------------------------------------------------
extern "C" void kernel_launch(void* const* d_in, const int* in_sizes, int n_in,
                              void* d_out, int out_size, void* d_ws, size_t ws_size,
                              hipStream_t stream)
{
    const float* rife  = (const float*)d_in[0];
    const float* d0    = (const float*)d_in[1];
    const float* d1    = (const float*)d_in[2];
    const float* wq    = (const float*)d_in[3];
    const float* bq    = (const float*)d_in[4];
    const float* wk    = (const float*)d_in[5];
    const float* bk    = (const float*)d_in[6];
    const float* wv    = (const float*)d_in[7];
    const float* bv    = (const float*)d_in[8];
    const float* w_off = (const float*)d_in[9];
    const float* b_off = (const float*)d_in[10];
    const float* dcnw  = (const float*)d_in[11];
    const float* gamma = (const float*)d_in[12];
    float* out = (float*)d_out;
    char* wsb  = (char*)d_ws;

    // ws layout (bytes)
    unsigned short* comb_t = (unsigned short*)(wsb);              // 33,554,432
    unsigned short* vbuf_t = (unsigned short*)(wsb + 33554432);   // 16,777,216
    float*          mws    = (float*)(wsb + 50331648);            //  4,718,592
    unsigned short* wT2    = (unsigned short*)(wsb + 55050240);   //  1,179,648
    unsigned short* dcnwT  = (unsigned short*)(wsb + 56229888);   //    294,912
    // total: ~56.5 MB

    wprep<<<2304, 256, 0, stream>>>(w_off, wT2);
    dprep<<<576, 256, 0, stream>>>(dcnw, dcnwT);
    qkv_gemm<<<dim3(64, 12, 8), 256, 0, stream>>>(rife, d0, d1, wq, bq, wk, bk, wv, bv, comb_t, vbuf_t);
    offconv_mfma<<<dim3(64, 8), 256, 0, stream>>>(comb_t, wT2, b_off, out, mws);
    dcn_fuse_mfma<<<1024, 256, 0, stream>>>(rife, dcnwT, gamma, vbuf_t, mws, out);
}

// Round 5
// 277.133 us; speedup vs baseline: 11.3085x; 1.5245x over previous
//
#include <hip/hip_runtime.h>
#include <math.h>

#define HW   4096
#define CDIM 256

typedef float f32x4  __attribute__((ext_vector_type(4)));
typedef short short8 __attribute__((ext_vector_type(8)));

// d_out layout (float offsets)
#define FUSED_SZ (4ULL*256*HW)
#define OFF_SZ   (4ULL*72*HW)

static __device__ __forceinline__ unsigned short f2b(float f) {
    unsigned u = __float_as_uint(f);
    unsigned r = (u + 0x7fffu + ((u >> 16) & 1u)) >> 16;
    return (unsigned short)r;
}
static __device__ __forceinline__ float b2f(short h) {
    return __uint_as_float(((unsigned)(unsigned short)h) << 16);
}

// ---------------------------------------------------------------------------
// Kernel 0a: one-time weight transpose  w_off[108][512][9] f32
//   -> wT2[kk][o(pad 128)][c] bf16   (1.18 MB, L2-resident)
// ---------------------------------------------------------------------------
__global__ __launch_bounds__(256) void wprep(const float* __restrict__ w_off,
                                             unsigned short* __restrict__ wT2)
{
    int idx = blockIdx.x * 256 + threadIdx.x;
    if (idx >= 9 * 128 * 512) return;
    int kk  = idx / (128 * 512);
    int rem = idx - kk * 128 * 512;
    int o = rem >> 9;
    int c = rem & 511;
    float v = (o < 108) ? w_off[((size_t)o * 512 + c) * 9 + kk] : 0.f;
    wT2[idx] = f2b(v);
}

// ---------------------------------------------------------------------------
// Kernel 0b: one-time transpose  dcn_w[256][64][3][3] f32 -> dcnwT[k][o][i] bf16
// ---------------------------------------------------------------------------
__global__ __launch_bounds__(256) void dprep(const float* __restrict__ dcn_w,
                                             unsigned short* __restrict__ dcnwT)
{
    int idx = blockIdx.x * 256 + threadIdx.x;
    if (idx >= 9 * 256 * 64) return;
    int k   = idx / (256 * 64);
    int rem = idx - k * 256 * 64;
    int o = rem >> 6;
    int i = rem & 63;
    dcnwT[idx] = f2b(dcn_w[((size_t)o * 64 + i) * 9 + k]);
}

// ---------------------------------------------------------------------------
// Kernel 0c: fuse wq|wk|wv -> wqkvT[768][256] bf16 (row-major [o][c], 384 KB)
// ---------------------------------------------------------------------------
__global__ __launch_bounds__(256) void qwprep(
    const float* __restrict__ wq, const float* __restrict__ wk,
    const float* __restrict__ wv, unsigned short* __restrict__ wqkvT)
{
    int idx = blockIdx.x * 256 + threadIdx.x;   // 768*256
    int o = idx >> 8;
    int c = idx & 255;
    float v = (o < 256) ? wq[(size_t)o * 256 + c]
            : (o < 512) ? wk[(size_t)(o - 256) * 256 + c]
                        : wv[(size_t)(o - 512) * 256 + c];
    wqkvT[idx] = f2b(v);
}

// ---------------------------------------------------------------------------
// Kernel 0d: transpose 12 input images NCHW f32 -> NHWC bf16
//   img 0..3 = rife[b], 4..7 = d0[b], 8..11 = d1[b]
//   xT[img][4096][256]
// ---------------------------------------------------------------------------
__global__ __launch_bounds__(256) void xprep(
    const float* __restrict__ rife, const float* __restrict__ d0,
    const float* __restrict__ d1, unsigned short* __restrict__ xT)
{
    const int pix0 = blockIdx.x * 64;
    const int img  = blockIdx.y;
    const int t    = threadIdx.x;

    const float* src = (img < 4) ? rife + (size_t)img * CDIM * HW
                     : (img < 8) ? d0 + (size_t)(img - 4) * CDIM * HW
                                 : d1 + (size_t)(img - 8) * CDIM * HW;
    unsigned short* dst = xT + (size_t)img * 4096 * 256;

    __shared__ float tile[64][65];

    for (int c0 = 0; c0 < 256; c0 += 64) {
        #pragma unroll
        for (int r = 0; r < 16; ++r) {
            int idx = t + r * 256;
            int c = idx >> 6, pp = idx & 63;
            tile[c][pp] = src[(size_t)(c0 + c) * HW + pix0 + pp];
        }
        __syncthreads();
        const int pix = t >> 2, cq = t & 3;
        const int cb = cq * 16;
        uint4 p0, p1;
        p0.x = (unsigned)f2b(tile[cb+0][pix])  | ((unsigned)f2b(tile[cb+1][pix])  << 16);
        p0.y = (unsigned)f2b(tile[cb+2][pix])  | ((unsigned)f2b(tile[cb+3][pix])  << 16);
        p0.z = (unsigned)f2b(tile[cb+4][pix])  | ((unsigned)f2b(tile[cb+5][pix])  << 16);
        p0.w = (unsigned)f2b(tile[cb+6][pix])  | ((unsigned)f2b(tile[cb+7][pix])  << 16);
        p1.x = (unsigned)f2b(tile[cb+8][pix])  | ((unsigned)f2b(tile[cb+9][pix])  << 16);
        p1.y = (unsigned)f2b(tile[cb+10][pix]) | ((unsigned)f2b(tile[cb+11][pix]) << 16);
        p1.z = (unsigned)f2b(tile[cb+12][pix]) | ((unsigned)f2b(tile[cb+13][pix]) << 16);
        p1.w = (unsigned)f2b(tile[cb+14][pix]) | ((unsigned)f2b(tile[cb+15][pix]) << 16);
        unsigned short* p = dst + (size_t)(pix0 + pix) * 256 + c0 + cb;
        *(uint4*)p = p0;
        *(uint4*)(p + 8) = p1;
        __syncthreads();
    }
}

// ---------------------------------------------------------------------------
// Kernel 1: QKV 1x1 convs as pure-register MFMA GEMM (no LDS, no barriers).
// Grid (pixtile, type{Q,K,V}, s); 4 waves; wave = 64 o x 64 pix, K=256.
// A,B fragments are direct 16B global loads (wqkvT L2-hot, xT streamed).
// Output: NHWC bf16, Q->comb_t[..][0:256], K->comb_t[..][256:512], V->vbuf_t.
// ---------------------------------------------------------------------------
__global__ __launch_bounds__(256) void qkv_mfma(
    const unsigned short* __restrict__ xT,
    const unsigned short* __restrict__ wqkvT,
    const float* __restrict__ bq, const float* __restrict__ bk,
    const float* __restrict__ bv,
    unsigned short* __restrict__ comb_t, unsigned short* __restrict__ vbuf_t)
{
    const int pix0 = blockIdx.x * 64;
    const int type = blockIdx.y;
    const int s    = blockIdx.z;
    const int t    = threadIdx.x;
    const int wvi  = t >> 6;
    const int lane = t & 63;
    const int q    = lane >> 4;
    const int rl   = lane & 15;

    const int img = (type == 0) ? (s & 3) : (4 + s);
    const short8* X = (const short8*)(xT + (size_t)img * 4096 * 256);          // 32 short8/pix
    const short8* W = (const short8*)(wqkvT + (size_t)(type * 256 + wvi * 64) * 256);
    const float* bias = (type == 0) ? bq : (type == 1) ? bk : bv;

    f32x4 acc[4][4];
    #pragma unroll
    for (int mf = 0; mf < 4; ++mf)
        #pragma unroll
        for (int nf = 0; nf < 4; ++nf)
            acc[mf][nf] = (f32x4){0.f, 0.f, 0.f, 0.f};

    #pragma unroll
    for (int c8 = 0; c8 < 32; c8 += 4) {     // 8 K-steps of 32 channels
        short8 a[4], b[4];
        #pragma unroll
        for (int mf = 0; mf < 4; ++mf)
            a[mf] = W[(size_t)(mf * 16 + rl) * 32 + c8 + q];
        #pragma unroll
        for (int nf = 0; nf < 4; ++nf)
            b[nf] = X[(size_t)(pix0 + nf * 16 + rl) * 32 + c8 + q];
        #pragma unroll
        for (int mf = 0; mf < 4; ++mf)
            #pragma unroll
            for (int nf = 0; nf < 4; ++nf)
                acc[mf][nf] = __builtin_amdgcn_mfma_f32_16x16x32_bf16(a[mf], b[nf], acc[mf][nf], 0, 0, 0);
    }

    const int CH = (type < 2) ? 512 : 256;
    unsigned short* dst = (type < 2)
        ? comb_t + (size_t)s * 4096 * 512 + type * 256
        : vbuf_t + (size_t)s * 4096 * 256;
    #pragma unroll
    for (int mf = 0; mf < 4; ++mf) {
        const int o_loc = wvi * 64 + mf * 16 + q * 4;
        const float4 bz = *(const float4*)(bias + o_loc);
        #pragma unroll
        for (int nf = 0; nf < 4; ++nf) {
            const int pix = pix0 + nf * 16 + rl;
            uint2 pk;
            pk.x = (unsigned)f2b(acc[mf][nf][0] + bz.x) | ((unsigned)f2b(acc[mf][nf][1] + bz.y) << 16);
            pk.y = (unsigned)f2b(acc[mf][nf][2] + bz.z) | ((unsigned)f2b(acc[mf][nf][3] + bz.w) << 16);
            *(uint2*)(dst + (size_t)pix * CH + o_loc) = pk;
        }
    }
}

// ---------------------------------------------------------------------------
// Kernel 2: 3x3 conv 512->108 as implicit GEMM on MFMA bf16.
// ---------------------------------------------------------------------------
__global__ __launch_bounds__(256) void offconv_mfma(
    const unsigned short* __restrict__ comb_t,
    const unsigned short* __restrict__ wT2,
    const float* __restrict__ b_off,
    float* __restrict__ dout, float* __restrict__ mask_ws)
{
    const int h = blockIdx.x;
    const int s = blockIdx.y;
    const int t = threadIdx.x;
    const int lane = t & 63;
    const int wid  = t >> 6;
    const int q    = lane >> 4;
    const int rl   = lane & 15;

    __shared__ __align__(16) unsigned short tb[198 * 32];

    const short8* cbv = (const short8*)comb_t + (size_t)s * 4096 * 64;
    const short8* wv  = (const short8*)wT2;

    f32x4 acc[2][4];
    #pragma unroll
    for (int ma = 0; ma < 2; ++ma)
        #pragma unroll
        for (int nf = 0; nf < 4; ++nf)
            acc[ma][nf] = (f32x4){0.f, 0.f, 0.f, 0.f};

    for (int c0 = 0; c0 < 512; c0 += 32) {
        const int c8 = c0 >> 3;
        short8 a[2][9];
        #pragma unroll
        for (int ma = 0; ma < 2; ++ma) {
            const int o = (wid * 2 + ma) * 16 + rl;
            #pragma unroll
            for (int kk = 0; kk < 9; ++kk)
                a[ma][kk] = wv[(size_t)(kk * 128 + o) * 64 + c8 + q];
        }
        __syncthreads();
        for (int idx = t; idx < 792; idx += 256) {
            int x = idx >> 2, cq = idx & 3;
            int ky = x / 66, xx = x - ky * 66;
            int hh = h + ky - 1, gx = xx - 1;
            short8 v = {0, 0, 0, 0, 0, 0, 0, 0};
            if (hh >= 0 && hh < 64 && gx >= 0 && gx < 64)
                v = cbv[(size_t)(hh * 64 + gx) * 64 + c8 + cq];
            *((short8*)tb + x * 4 + cq) = v;
        }
        __syncthreads();
        #pragma unroll
        for (int kk = 0; kk < 9; ++kk) {
            const int ky = kk / 3, kx = kk % 3;
            #pragma unroll
            for (int nf = 0; nf < 4; ++nf) {
                short8 b = *((const short8*)tb + (ky * 66 + nf * 16 + rl + kx) * 4 + q);
                acc[0][nf] = __builtin_amdgcn_mfma_f32_16x16x32_bf16(a[0][kk], b, acc[0][nf], 0, 0, 0);
                acc[1][nf] = __builtin_amdgcn_mfma_f32_16x16x32_bf16(a[1][kk], b, acc[1][nf], 0, 0, 0);
            }
        }
    }

    const size_t obase = FUSED_SZ + (s < 4 ? 0 : OFF_SZ) + (size_t)(s & 3) * 72 * HW + (size_t)h * 64;
    const size_t mbase = (size_t)s * 36 * HW + (size_t)h * 64;
    #pragma unroll
    for (int ma = 0; ma < 2; ++ma) {
        #pragma unroll
        for (int r = 0; r < 4; ++r) {
            const int o = (wid * 2 + ma) * 16 + q * 4 + r;
            if (o >= 108) continue;
            const float bz = b_off[o];
            #pragma unroll
            for (int nf = 0; nf < 4; ++nf) {
                const int w = nf * 16 + rl;
                float v = acc[ma][nf][r] + bz;
                if (o < 72)
                    dout[obase + (size_t)o * HW + w] = v;
                else
                    mask_ws[mbase + (size_t)(o - 72) * HW + w] = 1.f / (1.f + expf(-v));
            }
        }
    }
}

// ---------------------------------------------------------------------------
// Kernel 3: deformable conv + residual fuse, MFMA bf16, zero LDS / barriers.
// ---------------------------------------------------------------------------
__global__ __launch_bounds__(256) void dcn_fuse_mfma(
    const float* __restrict__ rife, const unsigned short* __restrict__ dcnwT,
    const float* __restrict__ gamma,
    const unsigned short* __restrict__ vbuf_t, const float* __restrict__ mask_ws,
    float* __restrict__ dout)
{
    const int bid = blockIdx.x;
    const int c   = bid & 15;
    const int h   = bid >> 4;
    const int b   = c >> 2;
    const int g   = c & 3;
    const int t    = threadIdx.x;
    const int wv   = t >> 6;
    const int lane = t & 63;
    const int q    = lane >> 4;
    const int rl   = lane & 15;
    const int pix  = wv * 16 + rl;

    const short8* aT = (const short8*)dcnwT;

    f32x4 acc[4];
    #pragma unroll
    for (int ma = 0; ma < 4; ++ma) acc[ma] = (f32x4){0.f, 0.f, 0.f, 0.f};

    for (int k = 0; k < 9; ++k) {
        const int ky = k / 3, kx = k % 3;
        short8 a[4][2];
        #pragma unroll
        for (int ma = 0; ma < 4; ++ma)
            #pragma unroll
            for (int ks = 0; ks < 2; ++ks)
                a[ma][ks] = aT[(size_t)(k * 256 + g * 64 + ma * 16 + rl) * 8 + ks * 4 + q];

        #pragma unroll
        for (int sbi = 0; sbi < 2; ++sbi) {
            const int sb = b + sbi * 4;
            const size_t obase = FUSED_SZ + (sb < 4 ? 0 : OFF_SZ)
                               + (size_t)(sb & 3) * 72 * HW
                               + (size_t)(g * 18 + k * 2) * HW + (size_t)h * 64 + pix;
            const float oy = dout[obase];
            const float ox = dout[obase + HW];
            const float m  = mask_ws[(size_t)sb * 36 * HW + (size_t)(g * 9 + k) * HW + (size_t)h * 64 + pix];

            const float py = oy + (float)(h - 1 + ky);
            const float px = ox + (float)(pix - 1 + kx);
            const float y0f = floorf(py), x0f = floorf(px);
            const float fy = py - y0f, fx = px - x0f;
            const int y0 = (int)y0f, x0 = (int)x0f;
            const bool vy0 = (y0 >= 0) && (y0 < 64);
            const bool vy1 = (y0 >= -1) && (y0 < 63);
            const bool vx0 = (x0 >= 0) && (x0 < 64);
            const bool vx1 = (x0 >= -1) && (x0 < 63);
            const float w00 = (1.f - fy) * (1.f - fx) * m * (float)(vy0 && vx0);
            const float w01 = (1.f - fy) * fx        * m * (float)(vy0 && vx1);
            const float w10 = fy * (1.f - fx)        * m * (float)(vy1 && vx0);
            const float w11 = fy * fx                * m * (float)(vy1 && vx1);
            const int yc0 = min(max(y0, 0), 63),     yc1 = min(max(y0 + 1, 0), 63);
            const int xc0 = min(max(x0, 0), 63),     xc1 = min(max(x0 + 1, 0), 63);
            const size_t o00 = (size_t)(yc0 * 64 + xc0) * 256;
            const size_t o01 = (size_t)(yc0 * 64 + xc1) * 256;
            const size_t o10 = (size_t)(yc1 * 64 + xc0) * 256;
            const size_t o11 = (size_t)(yc1 * 64 + xc1) * 256;

            const unsigned short* Vb = vbuf_t + (size_t)sb * 4096 * 256 + g * 64 + q * 8;

            short8 v00a = *(const short8*)(Vb + o00);
            short8 v01a = *(const short8*)(Vb + o01);
            short8 v10a = *(const short8*)(Vb + o10);
            short8 v11a = *(const short8*)(Vb + o11);
            short8 v00b = *(const short8*)(Vb + o00 + 32);
            short8 v01b = *(const short8*)(Vb + o01 + 32);
            short8 v10b = *(const short8*)(Vb + o10 + 32);
            short8 v11b = *(const short8*)(Vb + o11 + 32);

            short8 bf0, bf1;
            #pragma unroll
            for (int cc = 0; cc < 8; ++cc) {
                float s0 = w00 * b2f(v00a[cc]) + w01 * b2f(v01a[cc])
                         + w10 * b2f(v10a[cc]) + w11 * b2f(v11a[cc]);
                float s1 = w00 * b2f(v00b[cc]) + w01 * b2f(v01b[cc])
                         + w10 * b2f(v10b[cc]) + w11 * b2f(v11b[cc]);
                bf0[cc] = (short)f2b(s0);
                bf1[cc] = (short)f2b(s1);
            }
            acc[0] = __builtin_amdgcn_mfma_f32_16x16x32_bf16(a[0][0], bf0, acc[0], 0, 0, 0);
            acc[1] = __builtin_amdgcn_mfma_f32_16x16x32_bf16(a[1][0], bf0, acc[1], 0, 0, 0);
            acc[2] = __builtin_amdgcn_mfma_f32_16x16x32_bf16(a[2][0], bf0, acc[2], 0, 0, 0);
            acc[3] = __builtin_amdgcn_mfma_f32_16x16x32_bf16(a[3][0], bf0, acc[3], 0, 0, 0);
            acc[0] = __builtin_amdgcn_mfma_f32_16x16x32_bf16(a[0][1], bf1, acc[0], 0, 0, 0);
            acc[1] = __builtin_amdgcn_mfma_f32_16x16x32_bf16(a[1][1], bf1, acc[1], 0, 0, 0);
            acc[2] = __builtin_amdgcn_mfma_f32_16x16x32_bf16(a[2][1], bf1, acc[2], 0, 0, 0);
            acc[3] = __builtin_amdgcn_mfma_f32_16x16x32_bf16(a[3][1], bf1, acc[3], 0, 0, 0);
        }
    }

    const float gm = gamma[0];
    #pragma unroll
    for (int ma = 0; ma < 4; ++ma) {
        #pragma unroll
        for (int r = 0; r < 4; ++r) {
            const int o = g * 64 + ma * 16 + q * 4 + r;
            const size_t addr = ((size_t)b * 256 + o) * HW + (size_t)h * 64 + pix;
            dout[addr] = rife[addr] + gm * acc[ma][r];
        }
    }
}

// ---------------------------------------------------------------------------
extern "C" void kernel_launch(void* const* d_in, const int* in_sizes, int n_in,
                              void* d_out, int out_size, void* d_ws, size_t ws_size,
                              hipStream_t stream)
{
    const float* rife  = (const float*)d_in[0];
    const float* d0    = (const float*)d_in[1];
    const float* d1    = (const float*)d_in[2];
    const float* wq    = (const float*)d_in[3];
    const float* bq    = (const float*)d_in[4];
    const float* wk    = (const float*)d_in[5];
    const float* bk    = (const float*)d_in[6];
    const float* wv    = (const float*)d_in[7];
    const float* bv    = (const float*)d_in[8];
    const float* w_off = (const float*)d_in[9];
    const float* b_off = (const float*)d_in[10];
    const float* dcnw  = (const float*)d_in[11];
    const float* gamma = (const float*)d_in[12];
    float* out = (float*)d_out;
    char* wsb  = (char*)d_ws;

    // ws layout (bytes)
    unsigned short* comb_t = (unsigned short*)(wsb);              // 33,554,432
    unsigned short* vbuf_t = (unsigned short*)(wsb + 33554432);   // 16,777,216
    float*          mws    = (float*)(wsb + 50331648);            //  4,718,592
    unsigned short* wT2    = (unsigned short*)(wsb + 55050240);   //  1,179,648
    unsigned short* dcnwT  = (unsigned short*)(wsb + 56229888);   //    294,912
    unsigned short* xT     = (unsigned short*)(wsb + 56524800);   // 25,165,824
    unsigned short* wqkvT  = (unsigned short*)(wsb + 81690624);   //    393,216
    // total: ~82.1 MB

    wprep<<<2304, 256, 0, stream>>>(w_off, wT2);
    dprep<<<576, 256, 0, stream>>>(dcnw, dcnwT);
    qwprep<<<768, 256, 0, stream>>>(wq, wk, wv, wqkvT);
    xprep<<<dim3(64, 12), 256, 0, stream>>>(rife, d0, d1, xT);
    qkv_mfma<<<dim3(64, 3, 8), 256, 0, stream>>>(xT, wqkvT, bq, bk, bv, comb_t, vbuf_t);
    offconv_mfma<<<dim3(64, 8), 256, 0, stream>>>(comb_t, wT2, b_off, out, mws);
    dcn_fuse_mfma<<<1024, 256, 0, stream>>>(rife, dcnwT, gamma, vbuf_t, mws, out);
}

// Round 6
// 257.867 us; speedup vs baseline: 12.1534x; 1.0747x over previous
//
#include <hip/hip_runtime.h>
#include <math.h>

#define HW   4096
#define CDIM 256

typedef float f32x4  __attribute__((ext_vector_type(4)));
typedef short short8 __attribute__((ext_vector_type(8)));

// d_out layout (float offsets)
#define FUSED_SZ (4ULL*256*HW)
#define OFF_SZ   (4ULL*72*HW)

static __device__ __forceinline__ unsigned short f2b(float f) {
    unsigned u = __float_as_uint(f);
    unsigned r = (u + 0x7fffu + ((u >> 16) & 1u)) >> 16;
    return (unsigned short)r;
}
static __device__ __forceinline__ float b2f(short h) {
    return __uint_as_float(((unsigned)(unsigned short)h) << 16);
}

// ---------------------------------------------------------------------------
// Kernel 0a: one-time weight transpose  w_off[108][512][9] f32
//   -> wT2[kk][o(pad 128)][c] bf16   (1.18 MB, L2-resident)
// ---------------------------------------------------------------------------
__global__ __launch_bounds__(256) void wprep(const float* __restrict__ w_off,
                                             unsigned short* __restrict__ wT2)
{
    int idx = blockIdx.x * 256 + threadIdx.x;
    if (idx >= 9 * 128 * 512) return;
    int kk  = idx / (128 * 512);
    int rem = idx - kk * 128 * 512;
    int o = rem >> 9;
    int c = rem & 511;
    float v = (o < 108) ? w_off[((size_t)o * 512 + c) * 9 + kk] : 0.f;
    wT2[idx] = f2b(v);
}

// ---------------------------------------------------------------------------
// Kernel 0b: one-time transpose  dcn_w[256][64][3][3] f32 -> dcnwT[k][o][i] bf16
// ---------------------------------------------------------------------------
__global__ __launch_bounds__(256) void dprep(const float* __restrict__ dcn_w,
                                             unsigned short* __restrict__ dcnwT)
{
    int idx = blockIdx.x * 256 + threadIdx.x;
    if (idx >= 9 * 256 * 64) return;
    int k   = idx / (256 * 64);
    int rem = idx - k * 256 * 64;
    int o = rem >> 6;
    int i = rem & 63;
    dcnwT[idx] = f2b(dcn_w[((size_t)o * 64 + i) * 9 + k]);
}

// ---------------------------------------------------------------------------
// Kernel 0c: fuse wq|wk|wv -> wqkvT[768][256] bf16 (row-major [o][c], 384 KB)
// ---------------------------------------------------------------------------
__global__ __launch_bounds__(256) void qwprep(
    const float* __restrict__ wq, const float* __restrict__ wk,
    const float* __restrict__ wv, unsigned short* __restrict__ wqkvT)
{
    int idx = blockIdx.x * 256 + threadIdx.x;   // 768*256
    int o = idx >> 8;
    int c = idx & 255;
    float v = (o < 256) ? wq[(size_t)o * 256 + c]
            : (o < 512) ? wk[(size_t)(o - 256) * 256 + c]
                        : wv[(size_t)(o - 512) * 256 + c];
    wqkvT[idx] = f2b(v);
}

// ---------------------------------------------------------------------------
// Kernel 0d: transpose 12 input images NCHW f32 -> NHWC bf16
//   img 0..3 = rife[b], 4..7 = d0[b], 8..11 = d1[b]
//   xT[img][4096][256]
// ---------------------------------------------------------------------------
__global__ __launch_bounds__(256) void xprep(
    const float* __restrict__ rife, const float* __restrict__ d0,
    const float* __restrict__ d1, unsigned short* __restrict__ xT)
{
    const int pix0 = blockIdx.x * 64;
    const int img  = blockIdx.y;
    const int t    = threadIdx.x;

    const float* src = (img < 4) ? rife + (size_t)img * CDIM * HW
                     : (img < 8) ? d0 + (size_t)(img - 4) * CDIM * HW
                                 : d1 + (size_t)(img - 8) * CDIM * HW;
    unsigned short* dst = xT + (size_t)img * 4096 * 256;

    __shared__ float tile[64][65];

    for (int c0 = 0; c0 < 256; c0 += 64) {
        #pragma unroll
        for (int r = 0; r < 16; ++r) {
            int idx = t + r * 256;
            int c = idx >> 6, pp = idx & 63;
            tile[c][pp] = src[(size_t)(c0 + c) * HW + pix0 + pp];
        }
        __syncthreads();
        const int pix = t >> 2, cq = t & 3;
        const int cb = cq * 16;
        uint4 p0, p1;
        p0.x = (unsigned)f2b(tile[cb+0][pix])  | ((unsigned)f2b(tile[cb+1][pix])  << 16);
        p0.y = (unsigned)f2b(tile[cb+2][pix])  | ((unsigned)f2b(tile[cb+3][pix])  << 16);
        p0.z = (unsigned)f2b(tile[cb+4][pix])  | ((unsigned)f2b(tile[cb+5][pix])  << 16);
        p0.w = (unsigned)f2b(tile[cb+6][pix])  | ((unsigned)f2b(tile[cb+7][pix])  << 16);
        p1.x = (unsigned)f2b(tile[cb+8][pix])  | ((unsigned)f2b(tile[cb+9][pix])  << 16);
        p1.y = (unsigned)f2b(tile[cb+10][pix]) | ((unsigned)f2b(tile[cb+11][pix]) << 16);
        p1.z = (unsigned)f2b(tile[cb+12][pix]) | ((unsigned)f2b(tile[cb+13][pix]) << 16);
        p1.w = (unsigned)f2b(tile[cb+14][pix]) | ((unsigned)f2b(tile[cb+15][pix]) << 16);
        unsigned short* p = dst + (size_t)(pix0 + pix) * 256 + c0 + cb;
        *(uint4*)p = p0;
        *(uint4*)(p + 8) = p1;
        __syncthreads();
    }
}

// ---------------------------------------------------------------------------
// Kernel 1: QKV 1x1 convs as pure-register MFMA GEMM (no LDS, no barriers).
// ---------------------------------------------------------------------------
__global__ __launch_bounds__(256) void qkv_mfma(
    const unsigned short* __restrict__ xT,
    const unsigned short* __restrict__ wqkvT,
    const float* __restrict__ bq, const float* __restrict__ bk,
    const float* __restrict__ bv,
    unsigned short* __restrict__ comb_t, unsigned short* __restrict__ vbuf_t)
{
    const int pix0 = blockIdx.x * 64;
    const int type = blockIdx.y;
    const int s    = blockIdx.z;
    const int t    = threadIdx.x;
    const int wvi  = t >> 6;
    const int lane = t & 63;
    const int q    = lane >> 4;
    const int rl   = lane & 15;

    const int img = (type == 0) ? (s & 3) : (4 + s);
    const short8* X = (const short8*)(xT + (size_t)img * 4096 * 256);
    const short8* W = (const short8*)(wqkvT + (size_t)(type * 256 + wvi * 64) * 256);
    const float* bias = (type == 0) ? bq : (type == 1) ? bk : bv;

    f32x4 acc[4][4];
    #pragma unroll
    for (int mf = 0; mf < 4; ++mf)
        #pragma unroll
        for (int nf = 0; nf < 4; ++nf)
            acc[mf][nf] = (f32x4){0.f, 0.f, 0.f, 0.f};

    #pragma unroll
    for (int c8 = 0; c8 < 32; c8 += 4) {
        short8 a[4], b[4];
        #pragma unroll
        for (int mf = 0; mf < 4; ++mf)
            a[mf] = W[(size_t)(mf * 16 + rl) * 32 + c8 + q];
        #pragma unroll
        for (int nf = 0; nf < 4; ++nf)
            b[nf] = X[(size_t)(pix0 + nf * 16 + rl) * 32 + c8 + q];
        #pragma unroll
        for (int mf = 0; mf < 4; ++mf)
            #pragma unroll
            for (int nf = 0; nf < 4; ++nf)
                acc[mf][nf] = __builtin_amdgcn_mfma_f32_16x16x32_bf16(a[mf], b[nf], acc[mf][nf], 0, 0, 0);
    }

    const int CH = (type < 2) ? 512 : 256;
    unsigned short* dst = (type < 2)
        ? comb_t + (size_t)s * 4096 * 512 + type * 256
        : vbuf_t + (size_t)s * 4096 * 256;
    #pragma unroll
    for (int mf = 0; mf < 4; ++mf) {
        const int o_loc = wvi * 64 + mf * 16 + q * 4;
        const float4 bz = *(const float4*)(bias + o_loc);
        #pragma unroll
        for (int nf = 0; nf < 4; ++nf) {
            const int pix = pix0 + nf * 16 + rl;
            uint2 pk;
            pk.x = (unsigned)f2b(acc[mf][nf][0] + bz.x) | ((unsigned)f2b(acc[mf][nf][1] + bz.y) << 16);
            pk.y = (unsigned)f2b(acc[mf][nf][2] + bz.z) | ((unsigned)f2b(acc[mf][nf][3] + bz.w) << 16);
            *(uint2*)(dst + (size_t)pix * CH + o_loc) = pk;
        }
    }
}

// ---------------------------------------------------------------------------
// Kernel 2: 3x3 conv 512->108 as implicit GEMM on MFMA bf16.
// Round 5: XCD-partitioned grid (s = bid&7 -> XCD = s, comb slice L2-hot),
// double-buffered staging (issue-early/write-late), XOR bank swizzle
// q' = q ^ ((x>>1)&3) on LDS write+read (8 bank-groups per quarter-wave).
// ---------------------------------------------------------------------------
__global__ __launch_bounds__(256) void offconv_mfma(
    const unsigned short* __restrict__ comb_t,
    const unsigned short* __restrict__ wT2,
    const float* __restrict__ b_off,
    float* __restrict__ dout, float* __restrict__ mask_ws)
{
    const int bid = blockIdx.x;
    const int s = bid & 7;          // XCD = linear_bid % 8 = s
    const int h = bid >> 3;
    const int t = threadIdx.x;
    const int lane = t & 63;
    const int wid  = t >> 6;
    const int q    = lane >> 4;
    const int rl   = lane & 15;

    __shared__ __align__(16) unsigned short tb[2][792 * 8];   // 2 x 12.4 KB

    const short8* cbv = (const short8*)comb_t + (size_t)s * 4096 * 64;
    const short8* wv  = (const short8*)wT2;

    const int i1 = t + 256, i2 = t + 512, i3 = t + 768;

    // staging load: idx -> (x=row in 3*66 halo, cq=short8 within 32-ch slab)
    auto sload = [&](int idx, int c8) -> short8 {
        int x = idx >> 2, cq = idx & 3;
        int ky = x / 66, xx = x - ky * 66;
        int hh = h + ky - 1, gx = xx - 1;
        short8 v = {0, 0, 0, 0, 0, 0, 0, 0};
        if (hh >= 0 && hh < 64 && gx >= 0 && gx < 64)
            v = cbv[(size_t)(hh * 64 + gx) * 64 + c8 + cq];
        return v;
    };
    auto swrite = [&](unsigned short* buf, int idx, short8 v) {
        int x = idx >> 2, cq = idx & 3;
        int qs = cq ^ ((x >> 1) & 3);
        *((short8*)buf + x * 4 + qs) = v;
    };

    f32x4 acc[2][4];
    #pragma unroll
    for (int ma = 0; ma < 2; ++ma)
        #pragma unroll
        for (int nf = 0; nf < 4; ++nf)
            acc[ma][nf] = (f32x4){0.f, 0.f, 0.f, 0.f};

    // prologue: stage slab 0
    short8 r0 = sload(t, 0), r1 = sload(i1, 0), r2 = sload(i2, 0);
    short8 r3 = {0,0,0,0,0,0,0,0};
    if (i3 < 792) r3 = sload(i3, 0);
    swrite(tb[0], t, r0); swrite(tb[0], i1, r1); swrite(tb[0], i2, r2);
    if (i3 < 792) swrite(tb[0], i3, r3);
    __syncthreads();

    for (int sl = 0; sl < 16; ++sl) {
        const int c8 = sl * 4;
        // issue next slab's global loads early (latency hides under MFMA)
        if (sl < 15) {
            r0 = sload(t, c8 + 4); r1 = sload(i1, c8 + 4); r2 = sload(i2, c8 + 4);
            if (i3 < 792) r3 = sload(i3, c8 + 4);
        }
        // A-fragments for this slab (L2-hot wT2)
        short8 a[2][9];
        #pragma unroll
        for (int ma = 0; ma < 2; ++ma) {
            const int o = (wid * 2 + ma) * 16 + rl;
            #pragma unroll
            for (int kk = 0; kk < 9; ++kk)
                a[ma][kk] = wv[(size_t)(kk * 128 + o) * 64 + c8 + q];
        }
        const unsigned short* bufc = tb[sl & 1];
        #pragma unroll
        for (int kk = 0; kk < 9; ++kk) {
            const int ky = kk / 3, kx = kk % 3;
            #pragma unroll
            for (int nf = 0; nf < 4; ++nf) {
                const int xr = ky * 66 + nf * 16 + rl + kx;
                short8 b = *((const short8*)bufc + xr * 4 + (q ^ ((xr >> 1) & 3)));
                acc[0][nf] = __builtin_amdgcn_mfma_f32_16x16x32_bf16(a[0][kk], b, acc[0][nf], 0, 0, 0);
                acc[1][nf] = __builtin_amdgcn_mfma_f32_16x16x32_bf16(a[1][kk], b, acc[1][nf], 0, 0, 0);
            }
        }
        // write next slab into the other buffer (waits its own vmcnt only)
        if (sl < 15) {
            unsigned short* bufn = tb[(sl + 1) & 1];
            swrite(bufn, t, r0); swrite(bufn, i1, r1); swrite(bufn, i2, r2);
            if (i3 < 792) swrite(bufn, i3, r3);
        }
        __syncthreads();
    }

    const size_t obase = FUSED_SZ + (s < 4 ? 0 : OFF_SZ) + (size_t)(s & 3) * 72 * HW + (size_t)h * 64;
    const size_t mbase = (size_t)s * 36 * HW + (size_t)h * 64;
    #pragma unroll
    for (int ma = 0; ma < 2; ++ma) {
        #pragma unroll
        for (int r = 0; r < 4; ++r) {
            const int o = (wid * 2 + ma) * 16 + q * 4 + r;
            if (o >= 108) continue;
            const float bz = b_off[o];
            #pragma unroll
            for (int nf = 0; nf < 4; ++nf) {
                const int w = nf * 16 + rl;
                float v = acc[ma][nf][r] + bz;
                if (o < 72)
                    dout[obase + (size_t)o * HW + w] = v;
                else
                    mask_ws[mbase + (size_t)(o - 72) * HW + w] = 1.f / (1.f + expf(-v));
            }
        }
    }
}

// ---------------------------------------------------------------------------
// Kernel 3: deformable conv + residual fuse, MFMA bf16, zero LDS / barriers.
// ---------------------------------------------------------------------------
__global__ __launch_bounds__(256) void dcn_fuse_mfma(
    const float* __restrict__ rife, const unsigned short* __restrict__ dcnwT,
    const float* __restrict__ gamma,
    const unsigned short* __restrict__ vbuf_t, const float* __restrict__ mask_ws,
    float* __restrict__ dout)
{
    const int bid = blockIdx.x;
    const int c   = bid & 15;
    const int h   = bid >> 4;
    const int b   = c >> 2;
    const int g   = c & 3;
    const int t    = threadIdx.x;
    const int wv   = t >> 6;
    const int lane = t & 63;
    const int q    = lane >> 4;
    const int rl   = lane & 15;
    const int pix  = wv * 16 + rl;

    const short8* aT = (const short8*)dcnwT;

    f32x4 acc[4];
    #pragma unroll
    for (int ma = 0; ma < 4; ++ma) acc[ma] = (f32x4){0.f, 0.f, 0.f, 0.f};

    for (int k = 0; k < 9; ++k) {
        const int ky = k / 3, kx = k % 3;
        short8 a[4][2];
        #pragma unroll
        for (int ma = 0; ma < 4; ++ma)
            #pragma unroll
            for (int ks = 0; ks < 2; ++ks)
                a[ma][ks] = aT[(size_t)(k * 256 + g * 64 + ma * 16 + rl) * 8 + ks * 4 + q];

        #pragma unroll
        for (int sbi = 0; sbi < 2; ++sbi) {
            const int sb = b + sbi * 4;
            const size_t obase = FUSED_SZ + (sb < 4 ? 0 : OFF_SZ)
                               + (size_t)(sb & 3) * 72 * HW
                               + (size_t)(g * 18 + k * 2) * HW + (size_t)h * 64 + pix;
            const float oy = dout[obase];
            const float ox = dout[obase + HW];
            const float m  = mask_ws[(size_t)sb * 36 * HW + (size_t)(g * 9 + k) * HW + (size_t)h * 64 + pix];

            const float py = oy + (float)(h - 1 + ky);
            const float px = ox + (float)(pix - 1 + kx);
            const float y0f = floorf(py), x0f = floorf(px);
            const float fy = py - y0f, fx = px - x0f;
            const int y0 = (int)y0f, x0 = (int)x0f;
            const bool vy0 = (y0 >= 0) && (y0 < 64);
            const bool vy1 = (y0 >= -1) && (y0 < 63);
            const bool vx0 = (x0 >= 0) && (x0 < 64);
            const bool vx1 = (x0 >= -1) && (x0 < 63);
            const float w00 = (1.f - fy) * (1.f - fx) * m * (float)(vy0 && vx0);
            const float w01 = (1.f - fy) * fx        * m * (float)(vy0 && vx1);
            const float w10 = fy * (1.f - fx)        * m * (float)(vy1 && vx0);
            const float w11 = fy * fx                * m * (float)(vy1 && vx1);
            const int yc0 = min(max(y0, 0), 63),     yc1 = min(max(y0 + 1, 0), 63);
            const int xc0 = min(max(x0, 0), 63),     xc1 = min(max(x0 + 1, 0), 63);
            const size_t o00 = (size_t)(yc0 * 64 + xc0) * 256;
            const size_t o01 = (size_t)(yc0 * 64 + xc1) * 256;
            const size_t o10 = (size_t)(yc1 * 64 + xc0) * 256;
            const size_t o11 = (size_t)(yc1 * 64 + xc1) * 256;

            const unsigned short* Vb = vbuf_t + (size_t)sb * 4096 * 256 + g * 64 + q * 8;

            short8 v00a = *(const short8*)(Vb + o00);
            short8 v01a = *(const short8*)(Vb + o01);
            short8 v10a = *(const short8*)(Vb + o10);
            short8 v11a = *(const short8*)(Vb + o11);
            short8 v00b = *(const short8*)(Vb + o00 + 32);
            short8 v01b = *(const short8*)(Vb + o01 + 32);
            short8 v10b = *(const short8*)(Vb + o10 + 32);
            short8 v11b = *(const short8*)(Vb + o11 + 32);

            short8 bf0, bf1;
            #pragma unroll
            for (int cc = 0; cc < 8; ++cc) {
                float s0 = w00 * b2f(v00a[cc]) + w01 * b2f(v01a[cc])
                         + w10 * b2f(v10a[cc]) + w11 * b2f(v11a[cc]);
                float s1 = w00 * b2f(v00b[cc]) + w01 * b2f(v01b[cc])
                         + w10 * b2f(v10b[cc]) + w11 * b2f(v11b[cc]);
                bf0[cc] = (short)f2b(s0);
                bf1[cc] = (short)f2b(s1);
            }
            acc[0] = __builtin_amdgcn_mfma_f32_16x16x32_bf16(a[0][0], bf0, acc[0], 0, 0, 0);
            acc[1] = __builtin_amdgcn_mfma_f32_16x16x32_bf16(a[1][0], bf0, acc[1], 0, 0, 0);
            acc[2] = __builtin_amdgcn_mfma_f32_16x16x32_bf16(a[2][0], bf0, acc[2], 0, 0, 0);
            acc[3] = __builtin_amdgcn_mfma_f32_16x16x32_bf16(a[3][0], bf0, acc[3], 0, 0, 0);
            acc[0] = __builtin_amdgcn_mfma_f32_16x16x32_bf16(a[0][1], bf1, acc[0], 0, 0, 0);
            acc[1] = __builtin_amdgcn_mfma_f32_16x16x32_bf16(a[1][1], bf1, acc[1], 0, 0, 0);
            acc[2] = __builtin_amdgcn_mfma_f32_16x16x32_bf16(a[2][1], bf1, acc[2], 0, 0, 0);
            acc[3] = __builtin_amdgcn_mfma_f32_16x16x32_bf16(a[3][1], bf1, acc[3], 0, 0, 0);
        }
    }

    const float gm = gamma[0];
    #pragma unroll
    for (int ma = 0; ma < 4; ++ma) {
        #pragma unroll
        for (int r = 0; r < 4; ++r) {
            const int o = g * 64 + ma * 16 + q * 4 + r;
            const size_t addr = ((size_t)b * 256 + o) * HW + (size_t)h * 64 + pix;
            dout[addr] = rife[addr] + gm * acc[ma][r];
        }
    }
}

// ---------------------------------------------------------------------------
extern "C" void kernel_launch(void* const* d_in, const int* in_sizes, int n_in,
                              void* d_out, int out_size, void* d_ws, size_t ws_size,
                              hipStream_t stream)
{
    const float* rife  = (const float*)d_in[0];
    const float* d0    = (const float*)d_in[1];
    const float* d1    = (const float*)d_in[2];
    const float* wq    = (const float*)d_in[3];
    const float* bq    = (const float*)d_in[4];
    const float* wk    = (const float*)d_in[5];
    const float* bk    = (const float*)d_in[6];
    const float* wv    = (const float*)d_in[7];
    const float* bv    = (const float*)d_in[8];
    const float* w_off = (const float*)d_in[9];
    const float* b_off = (const float*)d_in[10];
    const float* dcnw  = (const float*)d_in[11];
    const float* gamma = (const float*)d_in[12];
    float* out = (float*)d_out;
    char* wsb  = (char*)d_ws;

    // ws layout (bytes)
    unsigned short* comb_t = (unsigned short*)(wsb);              // 33,554,432
    unsigned short* vbuf_t = (unsigned short*)(wsb + 33554432);   // 16,777,216
    float*          mws    = (float*)(wsb + 50331648);            //  4,718,592
    unsigned short* wT2    = (unsigned short*)(wsb + 55050240);   //  1,179,648
    unsigned short* dcnwT  = (unsigned short*)(wsb + 56229888);   //    294,912
    unsigned short* xT     = (unsigned short*)(wsb + 56524800);   // 25,165,824
    unsigned short* wqkvT  = (unsigned short*)(wsb + 81690624);   //    393,216
    // total: ~82.1 MB

    wprep<<<2304, 256, 0, stream>>>(w_off, wT2);
    dprep<<<576, 256, 0, stream>>>(dcnw, dcnwT);
    qwprep<<<768, 256, 0, stream>>>(wq, wk, wv, wqkvT);
    xprep<<<dim3(64, 12), 256, 0, stream>>>(rife, d0, d1, xT);
    qkv_mfma<<<dim3(64, 3, 8), 256, 0, stream>>>(xT, wqkvT, bq, bk, bv, comb_t, vbuf_t);
    offconv_mfma<<<512, 256, 0, stream>>>(comb_t, wT2, b_off, out, mws);
    dcn_fuse_mfma<<<1024, 256, 0, stream>>>(rife, dcnwT, gamma, vbuf_t, mws, out);
}

// Round 7
// 215.577 us; speedup vs baseline: 14.5376x; 1.1962x over previous
//
#include <hip/hip_runtime.h>
#include <math.h>

#define HW   4096
#define CDIM 256

typedef float f32x4  __attribute__((ext_vector_type(4)));
typedef short short8 __attribute__((ext_vector_type(8)));

// d_out layout (float offsets)
#define FUSED_SZ (4ULL*256*HW)
#define OFF_SZ   (4ULL*72*HW)

static __device__ __forceinline__ unsigned short f2b(float f) {
    unsigned u = __float_as_uint(f);
    unsigned r = (u + 0x7fffu + ((u >> 16) & 1u)) >> 16;
    return (unsigned short)r;
}
static __device__ __forceinline__ float b2f(short h) {
    return __uint_as_float(((unsigned)(unsigned short)h) << 16);
}
// packed f32x2 -> bf16x2 (lo = a, hi = b), RNE in HW
static __device__ __forceinline__ unsigned pk_bf16(float a, float b) {
    unsigned r;
    asm("v_cvt_pk_bf16_f32 %0, %1, %2" : "=v"(r) : "v"(a), "v"(b));
    return r;
}
union U8 { unsigned u[4]; short8 s; };

// ---------------------------------------------------------------------------
// Kernel 0a: w_off[108][512][9] f32 -> wT2[kk][slab16][o128][c32] bf16
// (A-fragment loads become wave-contiguous 1KB)
// ---------------------------------------------------------------------------
__global__ __launch_bounds__(256) void wprep(const float* __restrict__ w_off,
                                             unsigned short* __restrict__ wT2)
{
    int idx = blockIdx.x * 256 + threadIdx.x;
    if (idx >= 9 * 128 * 512) return;
    int kk  = idx / (128 * 512);
    int rem = idx - kk * 128 * 512;
    int o = rem >> 9;
    int c = rem & 511;
    float v = (o < 108) ? w_off[((size_t)o * 512 + c) * 9 + kk] : 0.f;
    size_t flat = ((size_t)(kk * 16 + (c >> 5)) * 128 + o) * 32 + (c & 31);
    wT2[flat] = f2b(v);
}

// ---------------------------------------------------------------------------
// Kernel 0b: dcn_w[256][64][3][3] f32 -> dcnwT[k][g][ks2][o64][c32] bf16
// ---------------------------------------------------------------------------
__global__ __launch_bounds__(256) void dprep(const float* __restrict__ dcn_w,
                                             unsigned short* __restrict__ dcnwT)
{
    int idx = blockIdx.x * 256 + threadIdx.x;
    if (idx >= 9 * 256 * 64) return;
    int k   = idx / (256 * 64);
    int rem = idx - k * 256 * 64;
    int og = rem >> 6;
    int i  = rem & 63;
    int g = og >> 6, ol = og & 63;
    size_t flat = ((size_t)((k * 4 + g) * 2 + (i >> 5)) * 64 + ol) * 32 + (i & 31);
    dcnwT[flat] = f2b(dcn_w[((size_t)og * 64 + i) * 9 + k]);
}

// ---------------------------------------------------------------------------
// Kernel 0c: fuse wq|wk|wv -> wqkvT[768][256] bf16
// ---------------------------------------------------------------------------
__global__ __launch_bounds__(256) void qwprep(
    const float* __restrict__ wq, const float* __restrict__ wk,
    const float* __restrict__ wv, unsigned short* __restrict__ wqkvT)
{
    int idx = blockIdx.x * 256 + threadIdx.x;   // 768*256
    int o = idx >> 8;
    int c = idx & 255;
    float v = (o < 256) ? wq[(size_t)o * 256 + c]
            : (o < 512) ? wk[(size_t)(o - 256) * 256 + c]
                        : wv[(size_t)(o - 512) * 256 + c];
    wqkvT[idx] = f2b(v);
}

// ---------------------------------------------------------------------------
// Kernel 0d: transpose 12 input images NCHW f32 -> NHWC bf16  xT[12][4096][256]
// ---------------------------------------------------------------------------
__global__ __launch_bounds__(256) void xprep(
    const float* __restrict__ rife, const float* __restrict__ d0,
    const float* __restrict__ d1, unsigned short* __restrict__ xT)
{
    const int pix0 = blockIdx.x * 64;
    const int img  = blockIdx.y;
    const int t    = threadIdx.x;

    const float* src = (img < 4) ? rife + (size_t)img * CDIM * HW
                     : (img < 8) ? d0 + (size_t)(img - 4) * CDIM * HW
                                 : d1 + (size_t)(img - 8) * CDIM * HW;
    unsigned short* dst = xT + (size_t)img * 4096 * 256;

    __shared__ float tile[64][65];

    for (int c0 = 0; c0 < 256; c0 += 64) {
        #pragma unroll
        for (int r = 0; r < 16; ++r) {
            int idx = t + r * 256;
            int c = idx >> 6, pp = idx & 63;
            tile[c][pp] = src[(size_t)(c0 + c) * HW + pix0 + pp];
        }
        __syncthreads();
        const int pix = t >> 2, cq = t & 3;
        const int cb = cq * 16;
        uint4 p0, p1;
        p0.x = (unsigned)f2b(tile[cb+0][pix])  | ((unsigned)f2b(tile[cb+1][pix])  << 16);
        p0.y = (unsigned)f2b(tile[cb+2][pix])  | ((unsigned)f2b(tile[cb+3][pix])  << 16);
        p0.z = (unsigned)f2b(tile[cb+4][pix])  | ((unsigned)f2b(tile[cb+5][pix])  << 16);
        p0.w = (unsigned)f2b(tile[cb+6][pix])  | ((unsigned)f2b(tile[cb+7][pix])  << 16);
        p1.x = (unsigned)f2b(tile[cb+8][pix])  | ((unsigned)f2b(tile[cb+9][pix])  << 16);
        p1.y = (unsigned)f2b(tile[cb+10][pix]) | ((unsigned)f2b(tile[cb+11][pix]) << 16);
        p1.z = (unsigned)f2b(tile[cb+12][pix]) | ((unsigned)f2b(tile[cb+13][pix]) << 16);
        p1.w = (unsigned)f2b(tile[cb+14][pix]) | ((unsigned)f2b(tile[cb+15][pix]) << 16);
        unsigned short* p = dst + (size_t)(pix0 + pix) * 256 + c0 + cb;
        *(uint4*)p = p0;
        *(uint4*)(p + 8) = p1;
        __syncthreads();
    }
}

// ---------------------------------------------------------------------------
// Kernel 1: QKV 1x1 convs as pure-register MFMA GEMM (no LDS, no barriers).
// ---------------------------------------------------------------------------
__global__ __launch_bounds__(256) void qkv_mfma(
    const unsigned short* __restrict__ xT,
    const unsigned short* __restrict__ wqkvT,
    const float* __restrict__ bq, const float* __restrict__ bk,
    const float* __restrict__ bv,
    unsigned short* __restrict__ comb_t, unsigned short* __restrict__ vbuf_t)
{
    const int pix0 = blockIdx.x * 64;
    const int type = blockIdx.y;
    const int s    = blockIdx.z;
    const int t    = threadIdx.x;
    const int wvi  = t >> 6;
    const int lane = t & 63;
    const int q    = lane >> 4;
    const int rl   = lane & 15;

    const int img = (type == 0) ? (s & 3) : (4 + s);
    const short8* X = (const short8*)(xT + (size_t)img * 4096 * 256);
    const short8* W = (const short8*)(wqkvT + (size_t)(type * 256 + wvi * 64) * 256);
    const float* bias = (type == 0) ? bq : (type == 1) ? bk : bv;

    f32x4 acc[4][4];
    #pragma unroll
    for (int mf = 0; mf < 4; ++mf)
        #pragma unroll
        for (int nf = 0; nf < 4; ++nf)
            acc[mf][nf] = (f32x4){0.f, 0.f, 0.f, 0.f};

    #pragma unroll
    for (int c8 = 0; c8 < 32; c8 += 4) {
        short8 a[4], b[4];
        #pragma unroll
        for (int mf = 0; mf < 4; ++mf)
            a[mf] = W[(size_t)(mf * 16 + rl) * 32 + c8 + q];
        #pragma unroll
        for (int nf = 0; nf < 4; ++nf)
            b[nf] = X[(size_t)(pix0 + nf * 16 + rl) * 32 + c8 + q];
        #pragma unroll
        for (int mf = 0; mf < 4; ++mf)
            #pragma unroll
            for (int nf = 0; nf < 4; ++nf)
                acc[mf][nf] = __builtin_amdgcn_mfma_f32_16x16x32_bf16(a[mf], b[nf], acc[mf][nf], 0, 0, 0);
    }

    const int CH = (type < 2) ? 512 : 256;
    unsigned short* dst = (type < 2)
        ? comb_t + (size_t)s * 4096 * 512 + type * 256
        : vbuf_t + (size_t)s * 4096 * 256;
    #pragma unroll
    for (int mf = 0; mf < 4; ++mf) {
        const int o_loc = wvi * 64 + mf * 16 + q * 4;
        const float4 bz = *(const float4*)(bias + o_loc);
        #pragma unroll
        for (int nf = 0; nf < 4; ++nf) {
            const int pix = pix0 + nf * 16 + rl;
            uint2 pk;
            pk.x = pk_bf16(acc[mf][nf][0] + bz.x, acc[mf][nf][1] + bz.y);
            pk.y = pk_bf16(acc[mf][nf][2] + bz.z, acc[mf][nf][3] + bz.w);
            *(uint2*)(dst + (size_t)pix * CH + o_loc) = pk;
        }
    }
}

// ---------------------------------------------------------------------------
// Kernel 2: 3x3 conv 512->108 as implicit GEMM on MFMA bf16.
// XCD-partitioned grid, double-buffered staging, XOR bank swizzle,
// coalesced A-fragment loads from the [kk][slab][o][q] layout.
// ---------------------------------------------------------------------------
__global__ __launch_bounds__(256) void offconv_mfma(
    const unsigned short* __restrict__ comb_t,
    const unsigned short* __restrict__ wT2,
    const float* __restrict__ b_off,
    float* __restrict__ dout, float* __restrict__ mask_ws)
{
    const int bid = blockIdx.x;
    const int s = bid & 7;          // XCD = linear_bid % 8 = s
    const int h = bid >> 3;
    const int t = threadIdx.x;
    const int lane = t & 63;
    const int wid  = t >> 6;
    const int q    = lane >> 4;
    const int rl   = lane & 15;

    __shared__ __align__(16) unsigned short tb[2][792 * 8];

    const short8* cbv = (const short8*)comb_t + (size_t)s * 4096 * 64;
    const short8* wv  = (const short8*)wT2;

    const int i1 = t + 256, i2 = t + 512, i3 = t + 768;

    auto sload = [&](int idx, int c8) -> short8 {
        int x = idx >> 2, cq = idx & 3;
        int ky = x / 66, xx = x - ky * 66;
        int hh = h + ky - 1, gx = xx - 1;
        short8 v = {0, 0, 0, 0, 0, 0, 0, 0};
        if (hh >= 0 && hh < 64 && gx >= 0 && gx < 64)
            v = cbv[(size_t)(hh * 64 + gx) * 64 + c8 + cq];
        return v;
    };
    auto swrite = [&](unsigned short* buf, int idx, short8 v) {
        int x = idx >> 2, cq = idx & 3;
        int qs = cq ^ ((x >> 1) & 3);
        *((short8*)buf + x * 4 + qs) = v;
    };

    f32x4 acc[2][4];
    #pragma unroll
    for (int ma = 0; ma < 2; ++ma)
        #pragma unroll
        for (int nf = 0; nf < 4; ++nf)
            acc[ma][nf] = (f32x4){0.f, 0.f, 0.f, 0.f};

    short8 r0 = sload(t, 0), r1 = sload(i1, 0), r2 = sload(i2, 0);
    short8 r3 = {0,0,0,0,0,0,0,0};
    if (i3 < 792) r3 = sload(i3, 0);
    swrite(tb[0], t, r0); swrite(tb[0], i1, r1); swrite(tb[0], i2, r2);
    if (i3 < 792) swrite(tb[0], i3, r3);
    __syncthreads();

    for (int sl = 0; sl < 16; ++sl) {
        const int c8 = sl * 4;
        if (sl < 15) {
            r0 = sload(t, c8 + 4); r1 = sload(i1, c8 + 4); r2 = sload(i2, c8 + 4);
            if (i3 < 792) r3 = sload(i3, c8 + 4);
        }
        // A-fragments: [kk][slab][o][q] layout -> wave-contiguous 1KB per (ma,kk)
        short8 a[2][9];
        #pragma unroll
        for (int ma = 0; ma < 2; ++ma) {
            const int o = (wid * 2 + ma) * 16 + rl;
            #pragma unroll
            for (int kk = 0; kk < 9; ++kk)
                a[ma][kk] = wv[((size_t)(kk * 16 + sl) * 128 + o) * 4 + q];
        }
        const unsigned short* bufc = tb[sl & 1];
        #pragma unroll
        for (int kk = 0; kk < 9; ++kk) {
            const int ky = kk / 3, kx = kk % 3;
            #pragma unroll
            for (int nf = 0; nf < 4; ++nf) {
                const int xr = ky * 66 + nf * 16 + rl + kx;
                short8 b = *((const short8*)bufc + xr * 4 + (q ^ ((xr >> 1) & 3)));
                acc[0][nf] = __builtin_amdgcn_mfma_f32_16x16x32_bf16(a[0][kk], b, acc[0][nf], 0, 0, 0);
                acc[1][nf] = __builtin_amdgcn_mfma_f32_16x16x32_bf16(a[1][kk], b, acc[1][nf], 0, 0, 0);
            }
        }
        if (sl < 15) {
            unsigned short* bufn = tb[(sl + 1) & 1];
            swrite(bufn, t, r0); swrite(bufn, i1, r1); swrite(bufn, i2, r2);
            if (i3 < 792) swrite(bufn, i3, r3);
        }
        __syncthreads();
    }

    const size_t obase = FUSED_SZ + (s < 4 ? 0 : OFF_SZ) + (size_t)(s & 3) * 72 * HW + (size_t)h * 64;
    const size_t mbase = (size_t)s * 36 * HW + (size_t)h * 64;
    #pragma unroll
    for (int ma = 0; ma < 2; ++ma) {
        #pragma unroll
        for (int r = 0; r < 4; ++r) {
            const int o = (wid * 2 + ma) * 16 + q * 4 + r;
            if (o >= 108) continue;
            const float bz = b_off[o];
            #pragma unroll
            for (int nf = 0; nf < 4; ++nf) {
                const int w = nf * 16 + rl;
                float v = acc[ma][nf][r] + bz;
                if (o < 72)
                    dout[obase + (size_t)o * HW + w] = v;
                else
                    mask_ws[mbase + (size_t)(o - 72) * HW + w] = 1.f / (1.f + expf(-v));
            }
        }
    }
}

// ---------------------------------------------------------------------------
// Kernel 3: deformable conv + residual fuse, MFMA bf16, zero LDS / barriers.
// Coalesced A-loads ([k][g][ks][o][q] layout) + depth-1 coord prefetch.
// ---------------------------------------------------------------------------
__global__ __launch_bounds__(256) void dcn_fuse_mfma(
    const float* __restrict__ rife, const unsigned short* __restrict__ dcnwT,
    const float* __restrict__ gamma,
    const unsigned short* __restrict__ vbuf_t, const float* __restrict__ mask_ws,
    float* __restrict__ dout)
{
    const int bid = blockIdx.x;
    const int c   = bid & 15;
    const int h   = bid >> 4;
    const int b   = c >> 2;
    const int g   = c & 3;
    const int t    = threadIdx.x;
    const int wv   = t >> 6;
    const int lane = t & 63;
    const int q    = lane >> 4;
    const int rl   = lane & 15;
    const int pix  = wv * 16 + rl;

    const short8* aT = (const short8*)dcnwT;

    f32x4 acc[4];
    #pragma unroll
    for (int ma = 0; ma < 4; ++ma) acc[ma] = (f32x4){0.f, 0.f, 0.f, 0.f};

    // coord bases (sb0 = b < 4, sb1 = b+4 >= 4)
    const size_t obA = FUSED_SZ + (size_t)b * 72 * HW + (size_t)(g * 18) * HW + (size_t)h * 64 + pix;
    const size_t obB = obA + OFF_SZ;
    const size_t mbA = (size_t)b * 36 * HW + (size_t)(g * 9) * HW + (size_t)h * 64 + pix;
    const size_t mbB = mbA + 4ULL * 36 * HW;

    auto body = [&](float pyv, float pxv, float mv, int sb, short8 (&af)[4][2]) {
        const float y0f = floorf(pyv), x0f = floorf(pxv);
        const float fy = pyv - y0f, fx = pxv - x0f;
        const int y0 = (int)y0f, x0 = (int)x0f;
        const bool vy0 = (y0 >= 0) && (y0 < 64);
        const bool vy1 = (y0 >= -1) && (y0 < 63);
        const bool vx0 = (x0 >= 0) && (x0 < 64);
        const bool vx1 = (x0 >= -1) && (x0 < 63);
        const float w00 = (1.f - fy) * (1.f - fx) * mv * (float)(vy0 && vx0);
        const float w01 = (1.f - fy) * fx        * mv * (float)(vy0 && vx1);
        const float w10 = fy * (1.f - fx)        * mv * (float)(vy1 && vx0);
        const float w11 = fy * fx                * mv * (float)(vy1 && vx1);
        const int yc0 = min(max(y0, 0), 63),     yc1 = min(max(y0 + 1, 0), 63);
        const int xc0 = min(max(x0, 0), 63),     xc1 = min(max(x0 + 1, 0), 63);
        const size_t o00 = (size_t)(yc0 * 64 + xc0) * 256;
        const size_t o01 = (size_t)(yc0 * 64 + xc1) * 256;
        const size_t o10 = (size_t)(yc1 * 64 + xc0) * 256;
        const size_t o11 = (size_t)(yc1 * 64 + xc1) * 256;

        const unsigned short* Vb = vbuf_t + (size_t)sb * 4096 * 256 + g * 64 + q * 8;

        short8 v00a = *(const short8*)(Vb + o00);
        short8 v01a = *(const short8*)(Vb + o01);
        short8 v10a = *(const short8*)(Vb + o10);
        short8 v11a = *(const short8*)(Vb + o11);
        short8 v00b = *(const short8*)(Vb + o00 + 32);
        short8 v01b = *(const short8*)(Vb + o01 + 32);
        short8 v10b = *(const short8*)(Vb + o10 + 32);
        short8 v11b = *(const short8*)(Vb + o11 + 32);

        U8 u0, u1;
        #pragma unroll
        for (int j = 0; j < 4; ++j) {
            const int ce = 2 * j, co = 2 * j + 1;
            float e0 = w00 * b2f(v00a[ce]) + w01 * b2f(v01a[ce])
                     + w10 * b2f(v10a[ce]) + w11 * b2f(v11a[ce]);
            float e1 = w00 * b2f(v00a[co]) + w01 * b2f(v01a[co])
                     + w10 * b2f(v10a[co]) + w11 * b2f(v11a[co]);
            u0.u[j] = pk_bf16(e0, e1);
            float f0 = w00 * b2f(v00b[ce]) + w01 * b2f(v01b[ce])
                     + w10 * b2f(v10b[ce]) + w11 * b2f(v11b[ce]);
            float f1 = w00 * b2f(v00b[co]) + w01 * b2f(v01b[co])
                     + w10 * b2f(v10b[co]) + w11 * b2f(v11b[co]);
            u1.u[j] = pk_bf16(f0, f1);
        }
        short8 bf0 = u0.s, bf1 = u1.s;
        acc[0] = __builtin_amdgcn_mfma_f32_16x16x32_bf16(af[0][0], bf0, acc[0], 0, 0, 0);
        acc[1] = __builtin_amdgcn_mfma_f32_16x16x32_bf16(af[1][0], bf0, acc[1], 0, 0, 0);
        acc[2] = __builtin_amdgcn_mfma_f32_16x16x32_bf16(af[2][0], bf0, acc[2], 0, 0, 0);
        acc[3] = __builtin_amdgcn_mfma_f32_16x16x32_bf16(af[3][0], bf0, acc[3], 0, 0, 0);
        acc[0] = __builtin_amdgcn_mfma_f32_16x16x32_bf16(af[0][1], bf1, acc[0], 0, 0, 0);
        acc[1] = __builtin_amdgcn_mfma_f32_16x16x32_bf16(af[1][1], bf1, acc[1], 0, 0, 0);
        acc[2] = __builtin_amdgcn_mfma_f32_16x16x32_bf16(af[2][1], bf1, acc[2], 0, 0, 0);
        acc[3] = __builtin_amdgcn_mfma_f32_16x16x32_bf16(af[3][1], bf1, acc[3], 0, 0, 0);
    };

    // prefetch k=0 coords
    float cyA = dout[obA],      cxA = dout[obA + HW],      cmA = mask_ws[mbA];
    float cyB = dout[obB],      cxB = dout[obB + HW],      cmB = mask_ws[mbB];

    #pragma unroll
    for (int k = 0; k < 9; ++k) {
        const int ky = k / 3, kx = k % 3;
        // A-fragments: coalesced 1KB wave loads (L2-hot, 288KB table)
        short8 af[4][2];
        #pragma unroll
        for (int ma = 0; ma < 4; ++ma)
            #pragma unroll
            for (int ks = 0; ks < 2; ++ks)
                af[ma][ks] = aT[((size_t)((k * 4 + g) * 2 + ks) * 64 + ma * 16 + rl) * 4 + q];
        // depth-1 coord prefetch
        float nyA = 0.f, nxA = 0.f, nmA = 0.f, nyB = 0.f, nxB = 0.f, nmB = 0.f;
        if (k < 8) {
            nyA = dout[obA + (size_t)((k + 1) * 2) * HW];
            nxA = dout[obA + (size_t)((k + 1) * 2 + 1) * HW];
            nmA = mask_ws[mbA + (size_t)(k + 1) * HW];
            nyB = dout[obB + (size_t)((k + 1) * 2) * HW];
            nxB = dout[obB + (size_t)((k + 1) * 2 + 1) * HW];
            nmB = mask_ws[mbB + (size_t)(k + 1) * HW];
        }
        body(cyA + (float)(h - 1 + ky), cxA + (float)(pix - 1 + kx), cmA, b,     af);
        body(cyB + (float)(h - 1 + ky), cxB + (float)(pix - 1 + kx), cmB, b + 4, af);
        if (k < 8) { cyA = nyA; cxA = nxA; cmA = nmA; cyB = nyB; cxB = nxB; cmB = nmB; }
    }

    const float gm = gamma[0];
    #pragma unroll
    for (int ma = 0; ma < 4; ++ma) {
        #pragma unroll
        for (int r = 0; r < 4; ++r) {
            const int o = g * 64 + ma * 16 + q * 4 + r;
            const size_t addr = ((size_t)b * 256 + o) * HW + (size_t)h * 64 + pix;
            dout[addr] = rife[addr] + gm * acc[ma][r];
        }
    }
}

// ---------------------------------------------------------------------------
extern "C" void kernel_launch(void* const* d_in, const int* in_sizes, int n_in,
                              void* d_out, int out_size, void* d_ws, size_t ws_size,
                              hipStream_t stream)
{
    const float* rife  = (const float*)d_in[0];
    const float* d0    = (const float*)d_in[1];
    const float* d1    = (const float*)d_in[2];
    const float* wq    = (const float*)d_in[3];
    const float* bq    = (const float*)d_in[4];
    const float* wk    = (const float*)d_in[5];
    const float* bk    = (const float*)d_in[6];
    const float* wv    = (const float*)d_in[7];
    const float* bv    = (const float*)d_in[8];
    const float* w_off = (const float*)d_in[9];
    const float* b_off = (const float*)d_in[10];
    const float* dcnw  = (const float*)d_in[11];
    const float* gamma = (const float*)d_in[12];
    float* out = (float*)d_out;
    char* wsb  = (char*)d_ws;

    // ws layout (bytes)
    unsigned short* comb_t = (unsigned short*)(wsb);              // 33,554,432
    unsigned short* vbuf_t = (unsigned short*)(wsb + 33554432);   // 16,777,216
    float*          mws    = (float*)(wsb + 50331648);            //  4,718,592
    unsigned short* wT2    = (unsigned short*)(wsb + 55050240);   //  1,179,648
    unsigned short* dcnwT  = (unsigned short*)(wsb + 56229888);   //    294,912
    unsigned short* xT     = (unsigned short*)(wsb + 56524800);   // 25,165,824
    unsigned short* wqkvT  = (unsigned short*)(wsb + 81690624);   //    393,216
    // total: ~82.1 MB

    wprep<<<2304, 256, 0, stream>>>(w_off, wT2);
    dprep<<<576, 256, 0, stream>>>(dcnw, dcnwT);
    qwprep<<<768, 256, 0, stream>>>(wq, wk, wv, wqkvT);
    xprep<<<dim3(64, 12), 256, 0, stream>>>(rife, d0, d1, xT);
    qkv_mfma<<<dim3(64, 3, 8), 256, 0, stream>>>(xT, wqkvT, bq, bk, bv, comb_t, vbuf_t);
    offconv_mfma<<<512, 256, 0, stream>>>(comb_t, wT2, b_off, out, mws);
    dcn_fuse_mfma<<<1024, 256, 0, stream>>>(rife, dcnwT, gamma, vbuf_t, mws, out);
}